// Round 19
// baseline (426.264 us; speedup 1.0000x reference)
//
#include <hip/hip_runtime.h>
#include <hip/hip_bf16.h>

namespace {

typedef unsigned short u16;
typedef unsigned int u32;

constexpr int D    = 256;
constexpr int H    = 8;
constexpr int DH   = 32;
constexpr int B    = 32;
constexpr int LQ   = 300;
constexpr int NQ   = B * LQ;      // 9600
constexpr int S    = 3840;
constexpr int MS   = B * S;       // 122880
constexpr int DFFN = 1024;

typedef __attribute__((ext_vector_type(8))) short bf16x8;
typedef __attribute__((ext_vector_type(4))) float f32x4;

__device__ inline u16 f2b(float x) {
  u32 u = __builtin_bit_cast(u32, x);
  u32 r = (u + 0x7FFFu + ((u >> 16) & 1u)) >> 16;
  return (u16)r;
}
__device__ inline u32 pk2(float a, float b) {
  return (u32)f2b(a) | ((u32)f2b(b) << 16);
}
__device__ inline void unpack2(u32 w, float& a, float& b) {
  a = __builtin_bit_cast(float, w << 16);
  b = __builtin_bit_cast(float, w & 0xffff0000u);
}

// ---------------------------------------------------------------------------
// Deform pass for 8 queries (rows q0..q0+7 of the 32-row block): tap table
// into owt (8x128 uint4 = 16 KB), gather from head-major V, sampled bf16
// written (swizzled) into Ast[32][256]. Identical arithmetic to deform_v4.
// ---------------------------------------------------------------------------
template<bool BOUNDARY>
__device__ inline void deform_phase8(
    int tid, int m0, int q0,
    const float* __restrict__ oa, const float* __restrict__ ref,
    const u16* __restrict__ value, uint4* owt /*[8*128]*/, char* Ast)
{
#pragma unroll
  for (int qq = 0; qq < 2; ++qq) {
    const int qr = (tid >> 7) + 4 * qq;          // 0..7
    const int bq = m0 + q0 + qr;
    const int t  = tid & 127;
    const int h = t >> 4;
    const int l = (t >> 2) & 3;
    const int p = t & 3;

    const float off    = oa[(size_t)bq * 256 + t];
    const float logit  = oa[(size_t)bq * 256 + 128 + t];
    const float center = ref[(size_t)bq * 8 + l * 2 + 0];
    const float width  = ref[(size_t)bq * 8 + l * 2 + 1];

    const float e = __expf(logit);
    float ssum = e;
    ssum += __shfl_xor(ssum, 1, 64);
    ssum += __shfl_xor(ssum, 2, 64);
    ssum += __shfl_xor(ssum, 4, 64);
    ssum += __shfl_xor(ssum, 8, 64);
    const float wa = e / ssum;

    const int T  = 2048 >> l;
    const int s0 = 4096 - (4096 >> l);
    float anchor = center;
    if (BOUNDARY) anchor += (p < 2 ? -0.5f : 0.5f) * width;
    const float loc = anchor + off * width * 0.125f;
    const float x = loc * (float)T - 0.5f;
    const float x0 = floorf(x);
    const float w = x - x0;
    const int i0 = (int)x0;
    const int i1 = i0 + 1;
    const float w0 = (i0 >= 0 && i0 < T) ? wa * (1.f - w) : 0.f;
    const float w1 = (i1 >= 0 && i1 < T) ? wa * w : 0.f;
    const int i0c = min(max(i0, 0), T - 1);
    const int i1c = min(max(i1, 0), T - 1);
    uint4 pack;
    pack.x = (u32)((h * S + s0 + i0c) * (DH * 2));
    pack.y = __builtin_bit_cast(u32, w0);
    pack.z = (u32)((h * S + s0 + i1c) * (DH * 2));
    pack.w = __builtin_bit_cast(u32, w1);
    owt[qr * 128 + t] = pack;
  }
  __syncthreads();

#pragma unroll
  for (int qq = 0; qq < 2; ++qq) {
    const int qr = (tid >> 7) + 4 * qq;
    const int ql = q0 + qr;
    const int bq = m0 + ql;
    const int b = bq / LQ;
    const int t = tid & 127;
    const int g  = t >> 4;
    const int ln = t & 15;
    const int qd = ln & 3;
    const int ts = ln >> 2;
    const char* vb = (const char*)(value + (size_t)b * H * S * DH) + qd * 16;
    float o[8] = {};
#pragma unroll
    for (int i = 0; i < 8; ++i) {
      const int rowidx = i * 4 + ts;
      const uint4 ow = owt[qr * 128 + g * 16 + (rowidx >> 1)];
      const u32 boff = (rowidx & 1) ? ow.z : ow.x;
      const float wt = __builtin_bit_cast(float, (rowidx & 1) ? ow.w : ow.y);
      const uint4 v = *(const uint4*)(vb + boff);
      float a0, a1;
      unpack2(v.x, a0, a1); o[0] += wt * a0; o[1] += wt * a1;
      unpack2(v.y, a0, a1); o[2] += wt * a0; o[3] += wt * a1;
      unpack2(v.z, a0, a1); o[4] += wt * a0; o[5] += wt * a1;
      unpack2(v.w, a0, a1); o[6] += wt * a0; o[7] += wt * a1;
    }
#pragma unroll
    for (int d = 0; d < 8; ++d) {
      o[d] += __shfl_xor(o[d], 4, 64);
      o[d] += __shfl_xor(o[d], 8, 64);
    }
    if (ts == 0) {
      const int col = g * DH + qd * 8;
      uint4 wv;
      wv.x = pk2(o[0], o[1]); wv.y = pk2(o[2], o[3]);
      wv.z = pk2(o[4], o[5]); wv.w = pk2(o[6], o[7]);
      *(uint4*)(Ast + ql * 512 + ((col * 2) ^ ((ql & 7) << 4))) = wv;
    }
  }
  __syncthreads();
}

// ---------------------------------------------------------------------------
// Fused q|k + v projection (round-8 version).
// ---------------------------------------------------------------------------
__global__ __launch_bounds__(256) void gemm_qkv(
    const u16* __restrict__ qbuf, const u16* __restrict__ tgtb,
    const u16* __restrict__ saqk_t, const u16* __restrict__ sav_t,
    const float* __restrict__ qkb, const float* __restrict__ vbias,
    u16* __restrict__ qkbuf, u16* __restrict__ vh)
{
  constexpr int K = 256, BK = 64, LDK = 72;
  __shared__ __align__(16) u16 sh[128 * LDK];
  u16* As = sh;
  u16* Bs = sh + 64 * LDK;
  const bool isv = blockIdx.x >= 8;
  const u16* A  = isv ? tgtb : qbuf;
  const u16* Bt = isv ? sav_t : saqk_t;
  const float* bias = isv ? vbias : qkb;
  u16* C = isv ? vh : qkbuf;
  const int N = isv ? 256 : 512;
  const int n0 = (isv ? (int)blockIdx.x - 8 : (int)blockIdx.x) * 64;
  const int m0 = blockIdx.y * 64;

  const int tid  = threadIdx.x;
  const int lane = tid & 63;
  const int wid  = tid >> 6;
  const int wm = wid >> 1, wn = wid & 1;

  f32x4 acc[2][2] = {};
  uint4 ra[2], rb[2];
  const int srow = tid >> 3, sch = (tid & 7) * 8;

#pragma unroll
  for (int i = 0; i < 2; ++i) {
    const int row = srow + i * 32;
    ra[i] = *(const uint4*)(A  + (size_t)(m0 + row) * K + sch);
    rb[i] = *(const uint4*)(Bt + (size_t)(n0 + row) * K + sch);
  }
  for (int t = 0; t < 4; ++t) {
#pragma unroll
    for (int i = 0; i < 2; ++i) {
      const int row = srow + i * 32;
      *(uint4*)(&As[row * LDK + sch]) = ra[i];
      *(uint4*)(&Bs[row * LDK + sch]) = rb[i];
    }
    __syncthreads();
    if (t + 1 < 4) {
      const int k0 = (t + 1) * BK;
#pragma unroll
      for (int i = 0; i < 2; ++i) {
        const int row = srow + i * 32;
        ra[i] = *(const uint4*)(A  + (size_t)(m0 + row) * K + k0 + sch);
        rb[i] = *(const uint4*)(Bt + (size_t)(n0 + row) * K + k0 + sch);
      }
    }
#pragma unroll
    for (int kk = 0; kk < 2; ++kk) {
      const int krd = kk * 32 + (lane >> 4) * 8;
      bf16x8 af[2], bf[2];
#pragma unroll
      for (int m = 0; m < 2; ++m)
        af[m] = *(const bf16x8*)(&As[(wm * 32 + (lane & 15) + 16 * m) * LDK + krd]);
#pragma unroll
      for (int n = 0; n < 2; ++n)
        bf[n] = *(const bf16x8*)(&Bs[(wn * 32 + (lane & 15) + 16 * n) * LDK + krd]);
#pragma unroll
      for (int m = 0; m < 2; ++m)
#pragma unroll
        for (int n = 0; n < 2; ++n)
          acc[m][n] = __builtin_amdgcn_mfma_f32_16x16x32_bf16(af[m], bf[n], acc[m][n], 0, 0, 0);
    }
    __syncthreads();
  }

  const int cr = (lane >> 4) * 4;
  const int cc = lane & 15;
  u16* stg = sh;
#pragma unroll
  for (int n = 0; n < 2; ++n) {
    const int lc = wn * 32 + n * 16 + cc;
    const float bv = bias[n0 + lc];
#pragma unroll
    for (int m = 0; m < 2; ++m) {
      const int lr0 = wm * 32 + m * 16 + cr;
#pragma unroll
      for (int r = 0; r < 4; ++r)
        stg[(lr0 + r) * LDK + lc] = f2b(acc[m][n][r] + bv);
    }
  }
  __syncthreads();
#pragma unroll
  for (int i = 0; i < 2; ++i) {
    const int c = tid + 256 * i;
    const int row = c >> 3, ch = c & 7;
    *(uint4*)(C + (size_t)(m0 + row) * N + n0 + ch * 8) =
        *(const uint4*)(&stg[row * LDK + ch * 8]);
  }
}

// ---------------------------------------------------------------------------
// Value projection v4, head-major output (B,H,S,DH), XCD-aware swizzle.
// (round-17 version)
// ---------------------------------------------------------------------------
__global__ __launch_bounds__(512) void gemm_val4(
    const float* __restrict__ A, const u16* __restrict__ Bt2,
    const float* __restrict__ bias2, u16* __restrict__ Vca, u16* __restrict__ Vse)
{
  __shared__ __align__(16) char shraw[33792];   // max(A 32768, stg 33792)
  char* Asw = shraw;
  const int tid  = threadIdx.x;
  const int lane = tid & 63;
  const int w    = tid >> 6;                    // 0..7
  const int bid  = blockIdx.x;
  const int nh   = (bid >> 3) & 1;
  const int m0   = ((bid >> 4) * 8 + (bid & 7)) * 64;
  u16* dst = nh ? Vse : Vca;
  const u16* Bt = Bt2 + nh * 256 * 256;
  const float* bias = bias2 + nh * 256;
  const int b  = m0 / S;
  const int s0 = m0 - b * S;

#pragma unroll
  for (int i = 0; i < 4; ++i) {
    const int idx = tid + 512 * i;
    const int row = idx >> 5, ch = idx & 31;
    const float* ap = A + (size_t)(m0 + row) * 256 + ch * 8;
    const float4 f0 = *(const float4*)(ap);
    const float4 f1 = *(const float4*)(ap + 4);
    uint4 pk;
    pk.x = pk2(f0.x, f0.y); pk.y = pk2(f0.z, f0.w);
    pk.z = pk2(f1.x, f1.y); pk.w = pk2(f1.z, f1.w);
    *(uint4*)(Asw + row * 512 + ((ch * 16) ^ ((row & 7) << 4))) = pk;
  }
  __syncthreads();

  f32x4 acc[4][2] = {};
  const u16* bb = Bt + (size_t)(w * 32 + (lane & 15)) * 256 + (lane >> 4) * 8;
  bf16x8 bcur[2], bnxt[2];
#pragma unroll
  for (int n = 0; n < 2; ++n) bcur[n] = *(const bf16x8*)(bb + n * 4096);

#pragma unroll
  for (int kk = 0; kk < 8; ++kk) {
    bf16x8 af[4];
    const int kb = kk * 64 + (lane >> 4) * 16;
#pragma unroll
    for (int m = 0; m < 4; ++m) {
      const int row = m * 16 + (lane & 15);
      af[m] = *(const bf16x8*)(Asw + row * 512 + (kb ^ ((row & 7) << 4)));
    }
    if (kk < 7) {
#pragma unroll
      for (int n = 0; n < 2; ++n)
        bnxt[n] = *(const bf16x8*)(bb + n * 4096 + (kk + 1) * 32);
    }
#pragma unroll
    for (int m = 0; m < 4; ++m)
#pragma unroll
      for (int n = 0; n < 2; ++n)
        acc[m][n] = __builtin_amdgcn_mfma_f32_16x16x32_bf16(af[m], bcur[n], acc[m][n], 0, 0, 0);
#pragma unroll
    for (int n = 0; n < 2; ++n) bcur[n] = bnxt[n];
  }
  __syncthreads();

  constexpr int STC = 264;
  u16* stg = (u16*)shraw;
  const int cr = (lane >> 4) * 4;
  const int cc = lane & 15;
#pragma unroll
  for (int n = 0; n < 2; ++n) {
    const int col = w * 32 + n * 16 + cc;
    const float bv = bias[col];
#pragma unroll
    for (int m = 0; m < 4; ++m) {
      const int r0 = m * 16 + cr;
#pragma unroll
      for (int r = 0; r < 4; ++r)
        stg[(r0 + r) * STC + col] = f2b(acc[m][n][r] + bv);
    }
  }
  __syncthreads();
  u16* vb = dst + (size_t)b * H * S * DH;
#pragma unroll
  for (int i = 0; i < 4; ++i) {
    const int c = tid + 512 * i;
    const int row = c >> 5, ch = c & 31;
    const int h = ch >> 2, dq = ch & 3;
    *(uint4*)(vb + ((size_t)h * S + (s0 + row)) * DH + dq * 8) =
        *(const uint4*)(&stg[row * STC + ch * 8]);
  }
}

// ---------------------------------------------------------------------------
// Fused GEMM + bias + residual + LN + (y+qpos)->bf16 + off/attn projection.
// (round-15 version; used once, after mha)
// ---------------------------------------------------------------------------
__global__ __launch_bounds__(1024) void gemm_lnoff(
    const u16* __restrict__ A, const u16* __restrict__ Bt,
    const float* __restrict__ bias, const float* __restrict__ res,
    const float* __restrict__ g, const float* __restrict__ be,
    const float* __restrict__ qpos,
    const u16* __restrict__ offw, const float* __restrict__ offb,
    float* __restrict__ fout, float* __restrict__ oaout)
{
  constexpr int K = 256, LDK = 72;
  __shared__ __align__(16) float ftile[64 * 264];
  u16* As = (u16*)ftile;
  u16* Bs = As + 64 * LDK;
  u16* aq = (u16*)ftile;
  const int tid  = threadIdx.x;
  const int lane = tid & 63;
  const int wid  = tid >> 6;
  const int wm = wid >> 2, wn = wid & 3;
  const int m0 = blockIdx.x * 64;

  f32x4 acc[4] = {};
  const bool am = tid < 512;
  const int arow = tid >> 3, ach = (tid & 7) * 8;

  uint4 ra = {};
  uint4 rb[2];
  if (am) ra = *(const uint4*)(A + (size_t)(m0 + arow) * K + ach);
#pragma unroll
  for (int i = 0; i < 2; ++i) {
    const int idx = tid + 1024 * i;
    const int brow = idx >> 3, bch = (idx & 7) * 8;
    rb[i] = *(const uint4*)(Bt + (size_t)brow * K + bch);
  }

  for (int t = 0; t < 4; ++t) {
    if (am) *(uint4*)(&As[arow * LDK + ach]) = ra;
#pragma unroll
    for (int i = 0; i < 2; ++i) {
      const int idx = tid + 1024 * i;
      const int brow = idx >> 3, bch = (idx & 7) * 8;
      *(uint4*)(&Bs[brow * LDK + bch]) = rb[i];
    }
    __syncthreads();
    if (t + 1 < 4) {
      const int k0 = (t + 1) * 64;
      if (am) ra = *(const uint4*)(A + (size_t)(m0 + arow) * K + k0 + ach);
#pragma unroll
      for (int i = 0; i < 2; ++i) {
        const int idx = tid + 1024 * i;
        const int brow = idx >> 3, bch = (idx & 7) * 8;
        rb[i] = *(const uint4*)(Bt + (size_t)brow * K + k0 + bch);
      }
    }
#pragma unroll
    for (int kk = 0; kk < 2; ++kk) {
      const int krd = kk * 32 + (lane >> 4) * 8;
      bf16x8 af, bf[4];
      af = *(const bf16x8*)(&As[(wm * 16 + (lane & 15)) * LDK + krd]);
#pragma unroll
      for (int n = 0; n < 4; ++n)
        bf[n] = *(const bf16x8*)(&Bs[(wn * 64 + n * 16 + (lane & 15)) * LDK + krd]);
#pragma unroll
      for (int n = 0; n < 4; ++n)
        acc[n] = __builtin_amdgcn_mfma_f32_16x16x32_bf16(af, bf[n], acc[n], 0, 0, 0);
    }
    __syncthreads();
  }

  const int cr = (lane >> 4) * 4;
  const int cc = lane & 15;
#pragma unroll
  for (int n = 0; n < 4; ++n) {
    const int col = wn * 64 + n * 16 + cc;
    const float bv = bias[col];
#pragma unroll
    for (int r = 0; r < 4; ++r)
      ftile[(wm * 16 + cr + r) * 264 + col] = acc[n][r] + bv;
  }
  __syncthreads();

  const int row = tid >> 4, s16 = tid & 15;
  const size_t grow = (size_t)(m0 + row) * 256;
  float vv[16];
  float sum = 0.f;
#pragma unroll
  for (int j = 0; j < 4; ++j) {
    const int col = s16 * 4 + j * 64;
    const float4 fv = *(const float4*)(&ftile[row * 264 + col]);
    const float4 rv = *(const float4*)(res + grow + col);
    vv[j * 4 + 0] = fv.x + rv.x; vv[j * 4 + 1] = fv.y + rv.y;
    vv[j * 4 + 2] = fv.z + rv.z; vv[j * 4 + 3] = fv.w + rv.w;
    sum += vv[j * 4 + 0] + vv[j * 4 + 1] + vv[j * 4 + 2] + vv[j * 4 + 3];
  }
  sum += __shfl_xor(sum, 1, 64);
  sum += __shfl_xor(sum, 2, 64);
  sum += __shfl_xor(sum, 4, 64);
  sum += __shfl_xor(sum, 8, 64);
  const float mean = sum * (1.f / 256.f);
  float sq = 0.f;
#pragma unroll
  for (int k = 0; k < 16; ++k) { const float d = vv[k] - mean; sq += d * d; }
  sq += __shfl_xor(sq, 1, 64);
  sq += __shfl_xor(sq, 2, 64);
  sq += __shfl_xor(sq, 4, 64);
  sq += __shfl_xor(sq, 8, 64);
  const float rstd = rsqrtf(sq * (1.f / 256.f) + 1e-5f);

  float yq[16];
#pragma unroll
  for (int j = 0; j < 4; ++j) {
    const int col = s16 * 4 + j * 64;
    const float4 gv = *(const float4*)(g + col);
    const float4 bv = *(const float4*)(be + col);
    const float4 qv = *(const float4*)(qpos + grow + col);
    float4 y;
    y.x = (vv[j * 4 + 0] - mean) * rstd * gv.x + bv.x;
    y.y = (vv[j * 4 + 1] - mean) * rstd * gv.y + bv.y;
    y.z = (vv[j * 4 + 2] - mean) * rstd * gv.z + bv.z;
    y.w = (vv[j * 4 + 3] - mean) * rstd * gv.w + bv.w;
    *(float4*)(fout + grow + col) = y;
    yq[j * 4 + 0] = y.x + qv.x; yq[j * 4 + 1] = y.y + qv.y;
    yq[j * 4 + 2] = y.z + qv.z; yq[j * 4 + 3] = y.w + qv.w;
  }
  __syncthreads();

#pragma unroll
  for (int j = 0; j < 4; ++j) {
    const int col = s16 * 4 + j * 64;
    uint2 pk;
    pk.x = pk2(yq[j * 4 + 0], yq[j * 4 + 1]);
    pk.y = pk2(yq[j * 4 + 2], yq[j * 4 + 3]);
    *(uint2*)(&aq[row * 264 + col]) = pk;
  }
  __syncthreads();

  f32x4 acc2[4] = {};
  const u16* bb = offw + (size_t)(wn * 64 + (lane & 15)) * 256 + (lane >> 4) * 8;
#pragma unroll
  for (int kk = 0; kk < 8; ++kk) {
    const bf16x8 af = *(const bf16x8*)(&aq[(wm * 16 + (lane & 15)) * 264 + kk * 32 + (lane >> 4) * 8]);
#pragma unroll
    for (int n = 0; n < 4; ++n) {
      const bf16x8 bf = *(const bf16x8*)(bb + (size_t)n * 16 * 256 + kk * 32);
      acc2[n] = __builtin_amdgcn_mfma_f32_16x16x32_bf16(af, bf, acc2[n], 0, 0, 0);
    }
  }
  __syncthreads();

#pragma unroll
  for (int n = 0; n < 4; ++n) {
    const int col = wn * 64 + n * 16 + cc;
    const float bv = offb[col];
#pragma unroll
    for (int r = 0; r < 4; ++r)
      ftile[(wm * 16 + cr + r) * 264 + col] = acc2[n][r] + bv;
  }
  __syncthreads();
#pragma unroll
  for (int i = 0; i < 4; ++i) {
    const int c = tid + 1024 * i;
    const int rw = c >> 6, ch = c & 63;
    *(float4*)(oaout + (size_t)(m0 + rw) * 256 + ch * 4) =
        *(const float4*)(&ftile[rw * 264 + ch * 4]);
  }
}

// ---------------------------------------------------------------------------
// Fused ca-deform + out-proj(caout) + LN(ln1) + (y+qpos) + off-proj(seoff).
// 32 rows / 512 thr, grid NQ/32. LDS 33.8 KB: Ast @0 (16K), owt @16K (16K,
// 4 deform passes of 8 queries); ftile/aq overlay after owt dead.
// ---------------------------------------------------------------------------
__global__ __launch_bounds__(512, 6) void deform_lnoff(
    const float* __restrict__ oa, const float* __restrict__ ref,
    const u16* __restrict__ value,
    const u16* __restrict__ Wout, const float* __restrict__ bout,
    const float* __restrict__ res, const float* __restrict__ g,
    const float* __restrict__ be, const float* __restrict__ qpos,
    const u16* __restrict__ offw, const float* __restrict__ offb,
    float* __restrict__ fout, float* __restrict__ oaout)
{
  __shared__ __align__(16) char sh[33792];
  char* Ast = sh;                                // [0, 16384)
  uint4* owt = (uint4*)(sh + 16384);             // [16384, 32768)
  float* ftile = (float*)sh;                     // [0, 33792), after owt dead
  u16* aq = (u16*)sh;                            // [0, 16896)
  const int tid  = threadIdx.x;
  const int lane = tid & 63;
  const int w    = tid >> 6;                     // 0..7
  const int m0   = blockIdx.x * 32;
  const int cr = (lane >> 4) * 4;
  const int cc = lane & 15;

  for (int q0 = 0; q0 < 32; q0 += 8)
    deform_phase8<false>(tid, m0, q0, oa, ref, value, owt, Ast);

  // ---- out-proj (caout): wave w -> cols w*32..+31, K=256
  f32x4 accB[2][2] = {};
  {
    const u16* bb = Wout + (size_t)(w * 32 + (lane & 15)) * 256 + (lane >> 4) * 8;
#pragma unroll
    for (int kk = 0; kk < 8; ++kk) {
      bf16x8 af[2];
      const int kb = kk * 64 + (lane >> 4) * 16;
#pragma unroll
      for (int m = 0; m < 2; ++m) {
        const int row = m * 16 + (lane & 15);
        af[m] = *(const bf16x8*)(Ast + row * 512 + (kb ^ ((row & 7) << 4)));
      }
#pragma unroll
      for (int n = 0; n < 2; ++n) {
        const bf16x8 bf = *(const bf16x8*)(bb + (size_t)n * 16 * 256 + kk * 32);
#pragma unroll
        for (int m = 0; m < 2; ++m)
          accB[m][n] = __builtin_amdgcn_mfma_f32_16x16x32_bf16(af[m], bf, accB[m][n], 0, 0, 0);
      }
    }
  }
  __syncthreads();   // Ast + owt consumed

#pragma unroll
  for (int n = 0; n < 2; ++n) {
    const int col = w * 32 + n * 16 + cc;
    const float bv = bout[col];
#pragma unroll
    for (int m = 0; m < 2; ++m)
#pragma unroll
      for (int r = 0; r < 4; ++r)
        ftile[(m * 16 + cr + r) * 264 + col] = accB[m][n][r] + bv;
  }
  __syncthreads();

  // ---- LN (ln1) + qpos
  const int row = tid >> 4, s16 = tid & 15;
  const size_t grow = (size_t)(m0 + row) * 256;
  float yq[16];
  {
    float vv[16];
    float sum = 0.f;
#pragma unroll
    for (int j = 0; j < 4; ++j) {
      const int col = s16 * 4 + j * 64;
      const float4 fv = *(const float4*)(&ftile[row * 264 + col]);
      const float4 rv = *(const float4*)(res + grow + col);
      vv[j * 4 + 0] = fv.x + rv.x; vv[j * 4 + 1] = fv.y + rv.y;
      vv[j * 4 + 2] = fv.z + rv.z; vv[j * 4 + 3] = fv.w + rv.w;
      sum += vv[j * 4 + 0] + vv[j * 4 + 1] + vv[j * 4 + 2] + vv[j * 4 + 3];
    }
    sum += __shfl_xor(sum, 1, 64);
    sum += __shfl_xor(sum, 2, 64);
    sum += __shfl_xor(sum, 4, 64);
    sum += __shfl_xor(sum, 8, 64);
    const float mean = sum * (1.f / 256.f);
    float sq = 0.f;
#pragma unroll
    for (int k = 0; k < 16; ++k) { const float d = vv[k] - mean; sq += d * d; }
    sq += __shfl_xor(sq, 1, 64);
    sq += __shfl_xor(sq, 2, 64);
    sq += __shfl_xor(sq, 4, 64);
    sq += __shfl_xor(sq, 8, 64);
    const float rstd = rsqrtf(sq * (1.f / 256.f) + 1e-5f);
#pragma unroll
    for (int j = 0; j < 4; ++j) {
      const int col = s16 * 4 + j * 64;
      const float4 gv = *(const float4*)(g + col);
      const float4 bv = *(const float4*)(be + col);
      const float4 qv = *(const float4*)(qpos + grow + col);
      float4 y;
      y.x = (vv[j * 4 + 0] - mean) * rstd * gv.x + bv.x;
      y.y = (vv[j * 4 + 1] - mean) * rstd * gv.y + bv.y;
      y.z = (vv[j * 4 + 2] - mean) * rstd * gv.z + bv.z;
      y.w = (vv[j * 4 + 3] - mean) * rstd * gv.w + bv.w;
      *(float4*)(fout + grow + col) = y;
      yq[j * 4 + 0] = y.x + qv.x; yq[j * 4 + 1] = y.y + qv.y;
      yq[j * 4 + 2] = y.z + qv.z; yq[j * 4 + 3] = y.w + qv.w;
    }
  }
  __syncthreads();

#pragma unroll
  for (int j = 0; j < 4; ++j) {
    const int col = s16 * 4 + j * 64;
    uint2 pk;
    pk.x = pk2(yq[j * 4 + 0], yq[j * 4 + 1]);
    pk.y = pk2(yq[j * 4 + 2], yq[j * 4 + 3]);
    *(uint2*)(&aq[row * 264 + col]) = pk;
  }
  __syncthreads();

  // ---- off-proj (seoff|seatt): wave w -> cols w*32..+31, K=256
  f32x4 acc2[2][2] = {};
  {
    const u16* bb = offw + (size_t)(w * 32 + (lane & 15)) * 256 + (lane >> 4) * 8;
#pragma unroll
    for (int kk = 0; kk < 8; ++kk) {
      bf16x8 af[2];
#pragma unroll
      for (int m = 0; m < 2; ++m)
        af[m] = *(const bf16x8*)(&aq[(m * 16 + (lane & 15)) * 264 + kk * 32 + (lane >> 4) * 8]);
#pragma unroll
      for (int n = 0; n < 2; ++n) {
        const bf16x8 bf = *(const bf16x8*)(bb + (size_t)n * 16 * 256 + kk * 32);
#pragma unroll
        for (int m = 0; m < 2; ++m)
          acc2[m][n] = __builtin_amdgcn_mfma_f32_16x16x32_bf16(af[m], bf, acc2[m][n], 0, 0, 0);
      }
    }
  }
  __syncthreads();

#pragma unroll
  for (int n = 0; n < 2; ++n) {
    const int col = w * 32 + n * 16 + cc;
    const float bv = offb[col];
#pragma unroll
    for (int m = 0; m < 2; ++m)
#pragma unroll
      for (int r = 0; r < 4; ++r)
        ftile[(m * 16 + cr + r) * 264 + col] = acc2[m][n][r] + bv;
  }
  __syncthreads();
#pragma unroll
  for (int i = 0; i < 4; ++i) {
    const int c = tid + 512 * i;
    const int rw = c >> 6, ch = c & 63;
    *(float4*)(oaout + (size_t)(m0 + rw) * 256 + ch * 4) =
        *(const float4*)(&ftile[rw * 264 + ch * 4]);
  }
}

// ---------------------------------------------------------------------------
// Fused tail2: se-deform + out-proj(seout) + LN(lnse) + ff1 + relu + ff2 +
// LN(ln3) -> d_out. 32 rows / 512 thr, grid NQ/32. LDS 33.8 KB:
// Ast @0 (16K); owt @16K (16K, 4 deform passes); ffh quarter @16K (16K,
// FFN split into 4 k-passes with partial ff2 accumulation).
// ---------------------------------------------------------------------------
__global__ __launch_bounds__(512, 6) void gemm_tail2(
    const float* __restrict__ oa, const float* __restrict__ ref,
    const u16* __restrict__ value,
    const u16* __restrict__ Wout, const float* __restrict__ bout,
    const float* __restrict__ res,
    const float* __restrict__ g1, const float* __restrict__ be1,
    const u16* __restrict__ B1t, const u16* __restrict__ B2t,
    const float* __restrict__ b1, const float* __restrict__ b2,
    const float* __restrict__ g2, const float* __restrict__ be2,
    float* __restrict__ fout)
{
  __shared__ __align__(16) char sh[33792];
  char* Ast = sh;                               // [0,16K)
  uint4* owt = (uint4*)(sh + 16384);            // [16K,32K) during deform
  char* ffh = sh + 16384;                       // [16K,32K) after deform
  float* ftile = (float*)sh;                    // [0,33792)
  const int tid  = threadIdx.x;
  const int lane = tid & 63;
  const int w    = tid >> 6;
  const int m0   = blockIdx.x * 32;
  const int cr = (lane >> 4) * 4;
  const int cc = lane & 15;

  for (int q0 = 0; q0 < 32; q0 += 8)
    deform_phase8<true>(tid, m0, q0, oa, ref, value, owt, Ast);

  // ---- out-proj (seout): wave w -> cols w*32..+31
  f32x4 accB[2][2] = {};
  {
    const u16* bb = Wout + (size_t)(w * 32 + (lane & 15)) * 256 + (lane >> 4) * 8;
#pragma unroll
    for (int kk = 0; kk < 8; ++kk) {
      bf16x8 af[2];
      const int kb = kk * 64 + (lane >> 4) * 16;
#pragma unroll
      for (int m = 0; m < 2; ++m) {
        const int row = m * 16 + (lane & 15);
        af[m] = *(const bf16x8*)(Ast + row * 512 + (kb ^ ((row & 7) << 4)));
      }
#pragma unroll
      for (int n = 0; n < 2; ++n) {
        const bf16x8 bf = *(const bf16x8*)(bb + (size_t)n * 16 * 256 + kk * 32);
#pragma unroll
        for (int m = 0; m < 2; ++m)
          accB[m][n] = __builtin_amdgcn_mfma_f32_16x16x32_bf16(af[m], bf, accB[m][n], 0, 0, 0);
      }
    }
  }
  __syncthreads();

#pragma unroll
  for (int n = 0; n < 2; ++n) {
    const int col = w * 32 + n * 16 + cc;
    const float bv = bout[col];
#pragma unroll
    for (int m = 0; m < 2; ++m)
#pragma unroll
      for (int r = 0; r < 4; ++r)
        ftile[(m * 16 + cr + r) * 264 + col] = accB[m][n][r] + bv;
  }
  __syncthreads();

  // ---- LN (lnse): y kept in registers
  const int row = tid >> 4, s16 = tid & 15;
  const size_t grow = (size_t)(m0 + row) * 256;
  float yv[16];
  {
    float vv[16];
    float sum = 0.f;
#pragma unroll
    for (int j = 0; j < 4; ++j) {
      const int col = s16 * 4 + j * 64;
      const float4 fv = *(const float4*)(&ftile[row * 264 + col]);
      const float4 rv = *(const float4*)(res + grow + col);
      vv[j * 4 + 0] = fv.x + rv.x; vv[j * 4 + 1] = fv.y + rv.y;
      vv[j * 4 + 2] = fv.z + rv.z; vv[j * 4 + 3] = fv.w + rv.w;
      sum += vv[j * 4 + 0] + vv[j * 4 + 1] + vv[j * 4 + 2] + vv[j * 4 + 3];
    }
    sum += __shfl_xor(sum, 1, 64);
    sum += __shfl_xor(sum, 2, 64);
    sum += __shfl_xor(sum, 4, 64);
    sum += __shfl_xor(sum, 8, 64);
    const float mean = sum * (1.f / 256.f);
    float sq = 0.f;
#pragma unroll
    for (int k = 0; k < 16; ++k) { const float d = vv[k] - mean; sq += d * d; }
    sq += __shfl_xor(sq, 1, 64);
    sq += __shfl_xor(sq, 2, 64);
    sq += __shfl_xor(sq, 4, 64);
    sq += __shfl_xor(sq, 8, 64);
    const float rstd = rsqrtf(sq * (1.f / 256.f) + 1e-5f);
#pragma unroll
    for (int j = 0; j < 4; ++j) {
      const int col = s16 * 4 + j * 64;
      const float4 gv = *(const float4*)(g1 + col);
      const float4 bv = *(const float4*)(be1 + col);
      yv[j * 4 + 0] = (vv[j * 4 + 0] - mean) * rstd * gv.x + bv.x;
      yv[j * 4 + 1] = (vv[j * 4 + 1] - mean) * rstd * gv.y + bv.y;
      yv[j * 4 + 2] = (vv[j * 4 + 2] - mean) * rstd * gv.z + bv.z;
      yv[j * 4 + 3] = (vv[j * 4 + 3] - mean) * rstd * gv.w + bv.w;
    }
  }
  __syncthreads();

  // bf16(y) -> Ast (swizzled)
#pragma unroll
  for (int j = 0; j < 4; ++j) {
    const int col = s16 * 4 + j * 64;
    uint2 pk;
    pk.x = pk2(yv[j * 4 + 0], yv[j * 4 + 1]);
    pk.y = pk2(yv[j * 4 + 2], yv[j * 4 + 3]);
    *(uint2*)(Ast + row * 512 + ((col * 2) ^ ((row & 7) << 4))) = pk;
  }
  __syncthreads();

  // ---- FFN in 4 k-passes: ff1 quarter -> ffh (16K), ff2 partial accumulate
  f32x4 acc2[2][2] = {};
  for (int hf = 0; hf < 4; ++hf) {
    {
      f32x4 acc1[2][2] = {};
      const u16* bb = B1t + (size_t)(hf * 256 + w * 32 + (lane & 15)) * 256 + (lane >> 4) * 8;
#pragma unroll
      for (int kk = 0; kk < 8; ++kk) {
        bf16x8 af[2];
        const int kb = kk * 64 + (lane >> 4) * 16;
#pragma unroll
        for (int m = 0; m < 2; ++m) {
          const int rw = m * 16 + (lane & 15);
          af[m] = *(const bf16x8*)(Ast + rw * 512 + (kb ^ ((rw & 7) << 4)));
        }
#pragma unroll
        for (int n = 0; n < 2; ++n) {
          const bf16x8 bf = *(const bf16x8*)(bb + (size_t)n * 16 * 256 + kk * 32);
#pragma unroll
          for (int m = 0; m < 2; ++m)
            acc1[m][n] = __builtin_amdgcn_mfma_f32_16x16x32_bf16(af[m], bf, acc1[m][n], 0, 0, 0);
        }
      }
#pragma unroll
      for (int n = 0; n < 2; ++n) {
        const int lcol = w * 32 + n * 16 + cc;         // 0..255 within quarter
        const float bv = b1[hf * 256 + lcol];
#pragma unroll
        for (int m = 0; m < 2; ++m) {
#pragma unroll
          for (int r = 0; r < 4; ++r) {
            const int rw = m * 16 + cr + r;
            const float x = fmaxf(acc1[m][n][r] + bv, 0.f);
            *(u16*)(ffh + rw * 512 + ((lcol * 2) ^ ((rw & 7) << 4))) = f2b(x);
          }
        }
      }
    }
    __syncthreads();

    {
      const u16* bb = B2t + (size_t)(w * 32 + (lane & 15)) * 1024 + (lane >> 4) * 8;
#pragma unroll
      for (int kk = 0; kk < 8; ++kk) {
        bf16x8 af[2];
        const int kb = kk * 64 + (lane >> 4) * 16;     // within 512-B quarter row
#pragma unroll
        for (int m = 0; m < 2; ++m) {
          const int rw = m * 16 + (lane & 15);
          af[m] = *(const bf16x8*)(ffh + rw * 512 + (kb ^ ((rw & 7) << 4)));
        }
#pragma unroll
        for (int n = 0; n < 2; ++n) {
          const bf16x8 bf = *(const bf16x8*)(bb + (size_t)n * 16 * 1024 + (hf * 8 + kk) * 32);
#pragma unroll
          for (int m = 0; m < 2; ++m)
            acc2[m][n] = __builtin_amdgcn_mfma_f32_16x16x32_bf16(af[m], bf, acc2[m][n], 0, 0, 0);
        }
      }
    }
    __syncthreads();
  }

  // acc2 + b2 -> ftile
#pragma unroll
  for (int n = 0; n < 2; ++n) {
    const int col = w * 32 + n * 16 + cc;
    const float bv = b2[col];
#pragma unroll
    for (int m = 0; m < 2; ++m)
#pragma unroll
      for (int r = 0; r < 4; ++r)
        ftile[(m * 16 + cr + r) * 264 + col] = acc2[m][n][r] + bv;
  }
  __syncthreads();

  // ---- final LN (ln3), residual = yv (in registers)
  {
    float vv[16];
    float sum = 0.f;
#pragma unroll
    for (int j = 0; j < 4; ++j) {
      const int col = s16 * 4 + j * 64;
      const float4 fv = *(const float4*)(&ftile[row * 264 + col]);
      vv[j * 4 + 0] = fv.x + yv[j * 4 + 0]; vv[j * 4 + 1] = fv.y + yv[j * 4 + 1];
      vv[j * 4 + 2] = fv.z + yv[j * 4 + 2]; vv[j * 4 + 3] = fv.w + yv[j * 4 + 3];
      sum += vv[j * 4 + 0] + vv[j * 4 + 1] + vv[j * 4 + 2] + vv[j * 4 + 3];
    }
    sum += __shfl_xor(sum, 1, 64);
    sum += __shfl_xor(sum, 2, 64);
    sum += __shfl_xor(sum, 4, 64);
    sum += __shfl_xor(sum, 8, 64);
    const float mean = sum * (1.f / 256.f);
    float sq = 0.f;
#pragma unroll
    for (int k = 0; k < 16; ++k) { const float d = vv[k] - mean; sq += d * d; }
    sq += __shfl_xor(sq, 1, 64);
    sq += __shfl_xor(sq, 2, 64);
    sq += __shfl_xor(sq, 4, 64);
    sq += __shfl_xor(sq, 8, 64);
    const float rstd = rsqrtf(sq * (1.f / 256.f) + 1e-5f);
#pragma unroll
    for (int j = 0; j < 4; ++j) {
      const int col = s16 * 4 + j * 64;
      const float4 gv = *(const float4*)(g2 + col);
      const float4 bv = *(const float4*)(be2 + col);
      float4 y;
      y.x = (vv[j * 4 + 0] - mean) * rstd * gv.x + bv.x;
      y.y = (vv[j * 4 + 1] - mean) * rstd * gv.y + bv.y;
      y.z = (vv[j * 4 + 2] - mean) * rstd * gv.z + bv.z;
      y.w = (vv[j * 4 + 3] - mean) * rstd * gv.w + bv.w;
      *(float4*)(fout + grow + col) = y;
    }
  }
}

// ---------------------------------------------------------------------------
// prep_all (round-8 version).
// ---------------------------------------------------------------------------
struct WSpec { const float* w; u16* wt; int K, N, blk0; };
struct WPack { WSpec s[14]; };

struct PrepArgs {
  const float *ca_off_b, *ca_attn_b, *se_off_b, *se_attn_b;
  const float *sa_qb, *sa_kb, *ca_val_b, *se_val_b;
  float *bias4, *qkb, *valb;
  const float *tgt, *qpos;
  u16 *tgtb, *qbuf;
  int n4, nwt;
};

__global__ __launch_bounds__(256) void prep_all(WPack p, PrepArgs a) {
  __shared__ float tile[32][33];
  const int b = blockIdx.x;
  if (b < a.nwt) {
    int i = 0;
#pragma unroll
    for (int j = 1; j < 14; ++j) if (b >= p.s[j].blk0) i = j;
    const float* w = p.s[i].w;
    u16* wt = p.s[i].wt;
    const int K = p.s[i].K, N = p.s[i].N;
    const int lb = b - p.s[i].blk0;
    const int ntN = N >> 5;
    const int tk = lb / ntN, tn = lb - tk * ntN;
    const int r = threadIdx.x >> 5, c = threadIdx.x & 31;
#pragma unroll
    for (int j = 0; j < 4; ++j)
      tile[r + j * 8][c] = w[(size_t)(tk * 32 + r + j * 8) * N + tn * 32 + c];
    __syncthreads();
#pragma unroll
    for (int j = 0; j < 4; ++j)
      wt[(size_t)(tn * 32 + r + j * 8) * K + tk * 32 + c] = f2b(tile[c][r + j * 8]);
  } else if (b == a.nwt) {
#pragma unroll
    for (int u = 0; u < 2; ++u) {
      const int t = threadIdx.x + 256 * u;
      a.bias4[t] = t < 128 ? a.ca_off_b[t] : t < 256 ? a.ca_attn_b[t - 128]
                 : t < 384 ? a.se_off_b[t - 256] : a.se_attn_b[t - 384];
      a.qkb[t]  = t < 256 ? a.sa_qb[t] : a.sa_kb[t - 256];
      a.valb[t] = t < 256 ? a.ca_val_b[t] : a.se_val_b[t - 256];
    }
  } else {
    const int i = (b - a.nwt - 1) * 256 + threadIdx.x;
    if (i < a.n4) {
      const float4 t = ((const float4*)a.tgt)[i];
      const float4 q = ((const float4*)a.qpos)[i];
      uint2 x, y;
      x.x = pk2(t.x, t.y); x.y = pk2(t.z, t.w);
      y.x = pk2(t.x + q.x, t.y + q.y); y.y = pk2(t.z + q.z, t.w + q.w);
      ((uint2*)a.tgtb)[i] = x;
      ((uint2*)a.qbuf)[i] = y;
    }
  }
}

// ---------------------------------------------------------------------------
// Self-attention: split-K softmax. (round-6 version)
// ---------------------------------------------------------------------------
__global__ __launch_bounds__(512) void mha_v2(
    const u16* __restrict__ qk, const u16* __restrict__ vh,
    u16* __restrict__ out)
{
  __shared__ __align__(16) float Ks[8 * 300 * 4];
  __shared__ __align__(16) float Vs[8 * 300 * 4];
  const int bh  = blockIdx.x & 255;
  const int seg = blockIdx.x >> 8;
  const int b = bh >> 3, h = bh & 7;
  const u16* kbase = qk + (size_t)b * LQ * 512 + 256 + h * DH;
  const u16* vbase = vh + (size_t)b * LQ * D + h * DH;
  for (int e = threadIdx.x; e < 300 * 8; e += 512) {
    const int r = e >> 3, j = e & 7;
    float4 f;
    const uint2 kv = *(const uint2*)(kbase + (size_t)r * 512 + j * 4);
    unpack2(kv.x, f.x, f.y);
    unpack2(kv.y, f.z, f.w);
    *(float4*)(&Ks[(j * 300 + r) * 4]) = f;
    const uint2 vv = *(const uint2*)(vbase + (size_t)r * D + j * 4);
    unpack2(vv.x, f.x, f.y);
    unpack2(vv.y, f.z, f.w);
    *(float4*)(&Vs[(j * 300 + r) * 4]) = f;
  }
  __syncthreads();

  const int lane = threadIdx.x & 63;
  const int lq = (threadIdx.x >> 6) * 16 + (lane >> 2);
  const int kc = lane & 3;
  const int q = seg * 128 + lq;
  if (q >= LQ) return;

  const u16* qrow = qk + (size_t)(b * LQ + q) * 512 + h * DH;
  float qv[DH];
#pragma unroll
  for (int c4 = 0; c4 < 4; ++c4) {
    const uint4 u = *(const uint4*)(qrow + c4 * 8);
    unpack2(u.x, qv[c4 * 8 + 0], qv[c4 * 8 + 1]);
    unpack2(u.y, qv[c4 * 8 + 2], qv[c4 * 8 + 3]);
    unpack2(u.z, qv[c4 * 8 + 4], qv[c4 * 8 + 5]);
    unpack2(u.w, qv[c4 * 8 + 6], qv[c4 * 8 + 7]);
  }
#pragma unroll
  for (int d = 0; d < DH; ++d) qv[d] *= 0.17677669529663689f;

  float o[DH] = {};
  float ssum = 0.f;
  const float* kp = &Ks[kc * 75 * 4];
  const float* vp = &Vs[kc * 75 * 4];
  for (int i = 0; i < 75; ++i) {
    float s = 0.f;
#pragma unroll
    for (int j = 0; j < 8; ++j) {
      const float4 kf = *(const float4*)(kp + i * 4 + j * 1200);
      s += qv[j * 4 + 0] * kf.x + qv[j * 4 + 1] * kf.y
         + qv[j * 4 + 2] * kf.z + qv[j * 4 + 3] * kf.w;
    }
    const float p = __expf(s);
    ssum += p;
#pragma unroll
    for (int j = 0; j < 8; ++j) {
      const float4 vf = *(const float4*)(vp + i * 4 + j * 1200);
      o[j * 4 + 0] += p * vf.x; o[j * 4 + 1] += p * vf.y;
      o[j * 4 + 2] += p * vf.z; o[j * 4 + 3] += p * vf.w;
    }
  }

  ssum += __shfl_xor(ssum, 1, 64);
  ssum += __shfl_xor(ssum, 2, 64);
#pragma unroll
  for (int d = 0; d < DH; ++d) {
    o[d] += __shfl_xor(o[d], 1, 64);
    o[d] += __shfl_xor(o[d], 2, 64);
  }
  const float inv = 1.f / ssum;

  u16* orow = out + (size_t)(b * LQ + q) * D + h * DH;
#pragma unroll
  for (int c = 0; c < 4; ++c) {
    if (kc == c) {
      uint4 w;
      w.x = pk2(o[c * 8 + 0] * inv, o[c * 8 + 1] * inv);
      w.y = pk2(o[c * 8 + 2] * inv, o[c * 8 + 3] * inv);
      w.z = pk2(o[c * 8 + 4] * inv, o[c * 8 + 5] * inv);
      w.w = pk2(o[c * 8 + 6] * inv, o[c * 8 + 7] * inv);
      *(uint4*)(orow + c * 8) = w;
    }
  }
}

}  // namespace

extern "C" void kernel_launch(void* const* d_in, const int* in_sizes, int n_in,
                              void* d_out, int out_size, void* d_ws, size_t ws_size,
                              hipStream_t stream)
{
  const float* tgt   = (const float*)d_in[0];
  const float* qpos  = (const float*)d_in[1];
  const float* ref   = (const float*)d_in[2];
  const float* src   = (const float*)d_in[3];
  const float* sa_qw = (const float*)d_in[6];
  const float* sa_kw = (const float*)d_in[7];
  const float* sa_vw = (const float*)d_in[8];
  const float* sa_ow = (const float*)d_in[9];
  const float* ff1_w = (const float*)d_in[10];
  const float* ff2_w = (const float*)d_in[11];
  const float* sa_qb = (const float*)d_in[12];
  const float* sa_kb = (const float*)d_in[13];
  const float* sa_vb = (const float*)d_in[14];
  const float* sa_ob = (const float*)d_in[15];
  const float* ff1_b = (const float*)d_in[16];
  const float* ff2_b = (const float*)d_in[17];
  const float* ca_off_w  = (const float*)d_in[18];
  const float* ca_off_b  = (const float*)d_in[19];
  const float* ca_attn_w = (const float*)d_in[20];
  const float* ca_attn_b = (const float*)d_in[21];
  const float* ca_val_w  = (const float*)d_in[22];
  const float* ca_val_b  = (const float*)d_in[23];
  const float* ca_out_w  = (const float*)d_in[24];
  const float* ca_out_b  = (const float*)d_in[25];
  const float* se_off_w  = (const float*)d_in[26];
  const float* se_off_b  = (const float*)d_in[27];
  const float* se_attn_w = (const float*)d_in[28];
  const float* se_attn_b = (const float*)d_in[29];
  const float* se_val_w  = (const float*)d_in[30];
  const float* se_val_b  = (const float*)d_in[31];
  const float* se_out_w  = (const float*)d_in[32];
  const float* se_out_b  = (const float*)d_in[33];
  const float* ln1_g  = (const float*)d_in[34];
  const float* ln1_b  = (const float*)d_in[35];
  const float* lnse_g = (const float*)d_in[36];
  const float* lnse_b = (const float*)d_in[37];
  const float* ln2_g  = (const float*)d_in[38];
  const float* ln2_b  = (const float*)d_in[39];
  const float* ln3_g  = (const float*)d_in[40];
  const float* ln3_b  = (const float*)d_in[41];

  const size_t ND = (size_t)NQ * D;       // 2,457,600
  const size_t MD = (size_t)MS * D;       // 31,457,280

  char* base = (char*)d_ws;
  size_t off = 0;
  auto alloc = [&](size_t bytes) -> void* {
    void* p = base + off;
    off += (bytes + 255) & ~(size_t)255;
    return p;
  };
  u16*  Vca  = (u16*)alloc(MD * 2);
  u16*  Vse  = (u16*)alloc(MD * 2);
  u16*  qkbuf = (u16*)alloc((size_t)NQ * 512 * 2);
  u16*  vh   = (u16*)alloc(ND * 2);
  u16*  qbuf = (u16*)alloc(ND * 2);
  u16*  smpb = (u16*)alloc(ND * 2);
  u16*  tgtb = (u16*)alloc(ND * 2);
  float* cur = (float*)alloc(ND * 4);
  float* oabuf = (float*)alloc((size_t)NQ * 256 * 4);
  float* bias4 = (float*)alloc(512 * 4);
  float* qkb   = (float*)alloc(512 * 4);
  float* valb  = (float*)alloc(512 * 4);

  WPack pk;
  int wi = 0, blk = 0;
  auto addw = [&](const float* w, int K, int N) -> u16* {
    u16* wt = (u16*)alloc((size_t)K * N * 2);
    pk.s[wi].w = w; pk.s[wi].wt = wt; pk.s[wi].K = K; pk.s[wi].N = N; pk.s[wi].blk0 = blk;
    blk += (K / 32) * (N / 32);
    ++wi;
    return wt;
  };
  u16* saq_t = addw(sa_qw, D, D);
  u16* sak_t = addw(sa_kw, D, D);        (void)sak_t;
  u16* sav_t = addw(sa_vw, D, D);
  u16* sao_t = addw(sa_ow, D, D);
  u16* ff1_t = addw(ff1_w, D, DFFN);
  u16* ff2_t = addw(ff2_w, DFFN, D);
  u16* caoff_t = addw(ca_off_w, D, 128);
  u16* caatt_t = addw(ca_attn_w, D, 128);  (void)caatt_t;
  u16* seoff_t = addw(se_off_w, D, 128);
  u16* seatt_t = addw(se_attn_w, D, 128);  (void)seatt_t;
  u16* caval_t = addw(ca_val_w, D, D);
  u16* seval_t = addw(se_val_w, D, D);     (void)seval_t;
  u16* caout_t = addw(ca_out_w, D, D);
  u16* seout_t = addw(se_out_w, D, D);

  const int n4 = (int)(ND / 4);            // 614400

  // ---- prep (weights + biases + tgt/qpos) in ONE dispatch ----
  PrepArgs pa;
  pa.ca_off_b = ca_off_b; pa.ca_attn_b = ca_attn_b;
  pa.se_off_b = se_off_b; pa.se_attn_b = se_attn_b;
  pa.sa_qb = sa_qb; pa.sa_kb = sa_kb; pa.ca_val_b = ca_val_b; pa.se_val_b = se_val_b;
  pa.bias4 = bias4; pa.qkb = qkb; pa.valb = valb;
  pa.tgt = tgt; pa.qpos = qpos; pa.tgtb = tgtb; pa.qbuf = qbuf;
  pa.n4 = n4; pa.nwt = blk;
  prep_all<<<blk + 1 + 2400, 256, 0, stream>>>(pk, pa);

  gemm_val4<<<(MS / 64) * 2, 512, 0, stream>>>(src, caval_t, valb, Vca, Vse);

  // ---- self-attention ----
  gemm_qkv<<<dim3(12, 150), 256, 0, stream>>>(qbuf, tgtb, saq_t, sav_t, qkb, sa_vb, qkbuf, vh);
  mha_v2<<<B * H * 3, 512, 0, stream>>>(qkbuf, vh, smpb);
  gemm_lnoff<<<NQ / 64, 1024, 0, stream>>>(smpb, sao_t, sa_ob, tgt, ln2_g, ln2_b,
                                           qpos, caoff_t, bias4, cur, oabuf);

  // ---- ca deform + out-proj + LN(ln1) + seoff projection (fused) ----
  deform_lnoff<<<NQ / 32, 512, 0, stream>>>(oabuf, ref, Vca,
                                            caout_t, ca_out_b, cur, ln1_g, ln1_b,
                                            qpos, seoff_t, bias4 + 256, cur, oabuf);

  // ---- se deform + out-proj + LN(lnse) + FFN + LN(ln3) -> d_out (fused) ----
  gemm_tail2<<<NQ / 32, 512, 0, stream>>>(oabuf, ref, Vse,
                                          seout_t, se_out_b, cur,
                                          lnse_g, lnse_b, ff1_t, ff2_t,
                                          ff1_b, ff2_b, ln3_g, ln3_b,
                                          (float*)d_out);
}

// Round 20
// 415.613 us; speedup vs baseline: 1.0256x; 1.0256x over previous
//
#include <hip/hip_runtime.h>
#include <hip/hip_bf16.h>

namespace {

typedef unsigned short u16;
typedef unsigned int u32;

constexpr int D    = 256;
constexpr int H    = 8;
constexpr int DH   = 32;
constexpr int B    = 32;
constexpr int LQ   = 300;
constexpr int NQ   = B * LQ;      // 9600
constexpr int S    = 3840;
constexpr int MS   = B * S;       // 122880
constexpr int DFFN = 1024;

typedef __attribute__((ext_vector_type(8))) short bf16x8;
typedef __attribute__((ext_vector_type(4))) float f32x4;

__device__ inline u16 f2b(float x) {
  u32 u = __builtin_bit_cast(u32, x);
  u32 r = (u + 0x7FFFu + ((u >> 16) & 1u)) >> 16;
  return (u16)r;
}
__device__ inline u32 pk2(float a, float b) {
  return (u32)f2b(a) | ((u32)f2b(b) << 16);
}
__device__ inline void unpack2(u32 w, float& a, float& b) {
  a = __builtin_bit_cast(float, w << 16);
  b = __builtin_bit_cast(float, w & 0xffff0000u);
}

// ---------------------------------------------------------------------------
// Fused deform phase for 32 queries / 512 threads: tap table into owt
// (32x128 uint4 = 64 KB), gather from head-major V, sampled bf16 written
// (swizzled) into Ast[32][256]. Identical arithmetic to deform_v4.
// ---------------------------------------------------------------------------
template<bool BOUNDARY>
__device__ inline void deform_phase(
    int tid, int m0,
    const float* __restrict__ oa, const float* __restrict__ ref,
    const u16* __restrict__ value, uint4* owt /*[32*128]*/, char* Ast)
{
#pragma unroll
  for (int qq = 0; qq < 8; ++qq) {
    const int ql = (tid >> 7) + 4 * qq;          // 0..31
    const int bq = m0 + ql;
    const int t  = tid & 127;
    const int h = t >> 4;
    const int l = (t >> 2) & 3;
    const int p = t & 3;

    const float off    = oa[(size_t)bq * 256 + t];
    const float logit  = oa[(size_t)bq * 256 + 128 + t];
    const float center = ref[(size_t)bq * 8 + l * 2 + 0];
    const float width  = ref[(size_t)bq * 8 + l * 2 + 1];

    const float e = __expf(logit);
    float ssum = e;
    ssum += __shfl_xor(ssum, 1, 64);
    ssum += __shfl_xor(ssum, 2, 64);
    ssum += __shfl_xor(ssum, 4, 64);
    ssum += __shfl_xor(ssum, 8, 64);
    const float wa = e / ssum;

    const int T  = 2048 >> l;
    const int s0 = 4096 - (4096 >> l);
    float anchor = center;
    if (BOUNDARY) anchor += (p < 2 ? -0.5f : 0.5f) * width;
    const float loc = anchor + off * width * 0.125f;
    const float x = loc * (float)T - 0.5f;
    const float x0 = floorf(x);
    const float w = x - x0;
    const int i0 = (int)x0;
    const int i1 = i0 + 1;
    const float w0 = (i0 >= 0 && i0 < T) ? wa * (1.f - w) : 0.f;
    const float w1 = (i1 >= 0 && i1 < T) ? wa * w : 0.f;
    const int i0c = min(max(i0, 0), T - 1);
    const int i1c = min(max(i1, 0), T - 1);
    uint4 pack;
    pack.x = (u32)((h * S + s0 + i0c) * (DH * 2));
    pack.y = __builtin_bit_cast(u32, w0);
    pack.z = (u32)((h * S + s0 + i1c) * (DH * 2));
    pack.w = __builtin_bit_cast(u32, w1);
    owt[ql * 128 + t] = pack;
  }
  __syncthreads();

#pragma unroll
  for (int qq = 0; qq < 8; ++qq) {
    const int ql = (tid >> 7) + 4 * qq;
    const int bq = m0 + ql;
    const int b = bq / LQ;
    const int t = tid & 127;
    const int g  = t >> 4;
    const int ln = t & 15;
    const int qd = ln & 3;
    const int ts = ln >> 2;
    const char* vb = (const char*)(value + (size_t)b * H * S * DH) + qd * 16;
    float o[8] = {};
#pragma unroll
    for (int i = 0; i < 8; ++i) {
      const int rowidx = i * 4 + ts;
      const uint4 ow = owt[ql * 128 + g * 16 + (rowidx >> 1)];
      const u32 boff = (rowidx & 1) ? ow.z : ow.x;
      const float wt = __builtin_bit_cast(float, (rowidx & 1) ? ow.w : ow.y);
      const uint4 v = *(const uint4*)(vb + boff);
      float a0, a1;
      unpack2(v.x, a0, a1); o[0] += wt * a0; o[1] += wt * a1;
      unpack2(v.y, a0, a1); o[2] += wt * a0; o[3] += wt * a1;
      unpack2(v.z, a0, a1); o[4] += wt * a0; o[5] += wt * a1;
      unpack2(v.w, a0, a1); o[6] += wt * a0; o[7] += wt * a1;
    }
#pragma unroll
    for (int d = 0; d < 8; ++d) {
      o[d] += __shfl_xor(o[d], 4, 64);
      o[d] += __shfl_xor(o[d], 8, 64);
    }
    if (ts == 0) {
      const int col = g * DH + qd * 8;
      uint4 wv;
      wv.x = pk2(o[0], o[1]); wv.y = pk2(o[2], o[3]);
      wv.z = pk2(o[4], o[5]); wv.w = pk2(o[6], o[7]);
      *(uint4*)(Ast + ql * 512 + ((col * 2) ^ ((ql & 7) << 4))) = wv;
    }
  }
  __syncthreads();
}

// ---------------------------------------------------------------------------
// Fused q|k + v projection (round-8 version).
// ---------------------------------------------------------------------------
__global__ __launch_bounds__(256) void gemm_qkv(
    const u16* __restrict__ qbuf, const u16* __restrict__ tgtb,
    const u16* __restrict__ saqk_t, const u16* __restrict__ sav_t,
    const float* __restrict__ qkb, const float* __restrict__ vbias,
    u16* __restrict__ qkbuf, u16* __restrict__ vh)
{
  constexpr int K = 256, BK = 64, LDK = 72;
  __shared__ __align__(16) u16 sh[128 * LDK];
  u16* As = sh;
  u16* Bs = sh + 64 * LDK;
  const bool isv = blockIdx.x >= 8;
  const u16* A  = isv ? tgtb : qbuf;
  const u16* Bt = isv ? sav_t : saqk_t;
  const float* bias = isv ? vbias : qkb;
  u16* C = isv ? vh : qkbuf;
  const int N = isv ? 256 : 512;
  const int n0 = (isv ? (int)blockIdx.x - 8 : (int)blockIdx.x) * 64;
  const int m0 = blockIdx.y * 64;

  const int tid  = threadIdx.x;
  const int lane = tid & 63;
  const int wid  = tid >> 6;
  const int wm = wid >> 1, wn = wid & 1;

  f32x4 acc[2][2] = {};
  uint4 ra[2], rb[2];
  const int srow = tid >> 3, sch = (tid & 7) * 8;

#pragma unroll
  for (int i = 0; i < 2; ++i) {
    const int row = srow + i * 32;
    ra[i] = *(const uint4*)(A  + (size_t)(m0 + row) * K + sch);
    rb[i] = *(const uint4*)(Bt + (size_t)(n0 + row) * K + sch);
  }
  for (int t = 0; t < 4; ++t) {
#pragma unroll
    for (int i = 0; i < 2; ++i) {
      const int row = srow + i * 32;
      *(uint4*)(&As[row * LDK + sch]) = ra[i];
      *(uint4*)(&Bs[row * LDK + sch]) = rb[i];
    }
    __syncthreads();
    if (t + 1 < 4) {
      const int k0 = (t + 1) * BK;
#pragma unroll
      for (int i = 0; i < 2; ++i) {
        const int row = srow + i * 32;
        ra[i] = *(const uint4*)(A  + (size_t)(m0 + row) * K + k0 + sch);
        rb[i] = *(const uint4*)(Bt + (size_t)(n0 + row) * K + k0 + sch);
      }
    }
#pragma unroll
    for (int kk = 0; kk < 2; ++kk) {
      const int krd = kk * 32 + (lane >> 4) * 8;
      bf16x8 af[2], bf[2];
#pragma unroll
      for (int m = 0; m < 2; ++m)
        af[m] = *(const bf16x8*)(&As[(wm * 32 + (lane & 15) + 16 * m) * LDK + krd]);
#pragma unroll
      for (int n = 0; n < 2; ++n)
        bf[n] = *(const bf16x8*)(&Bs[(wn * 32 + (lane & 15) + 16 * n) * LDK + krd]);
#pragma unroll
      for (int m = 0; m < 2; ++m)
#pragma unroll
        for (int n = 0; n < 2; ++n)
          acc[m][n] = __builtin_amdgcn_mfma_f32_16x16x32_bf16(af[m], bf[n], acc[m][n], 0, 0, 0);
    }
    __syncthreads();
  }

  const int cr = (lane >> 4) * 4;
  const int cc = lane & 15;
  u16* stg = sh;
#pragma unroll
  for (int n = 0; n < 2; ++n) {
    const int lc = wn * 32 + n * 16 + cc;
    const float bv = bias[n0 + lc];
#pragma unroll
    for (int m = 0; m < 2; ++m) {
      const int lr0 = wm * 32 + m * 16 + cr;
#pragma unroll
      for (int r = 0; r < 4; ++r)
        stg[(lr0 + r) * LDK + lc] = f2b(acc[m][n][r] + bv);
    }
  }
  __syncthreads();
#pragma unroll
  for (int i = 0; i < 2; ++i) {
    const int c = tid + 256 * i;
    const int row = c >> 3, ch = c & 7;
    *(uint4*)(C + (size_t)(m0 + row) * N + n0 + ch * 8) =
        *(const uint4*)(&stg[row * LDK + ch * 8]);
  }
}

// ---------------------------------------------------------------------------
// Value projection v4, head-major output (B,H,S,DH), XCD-aware swizzle.
// (round-17 version)
// ---------------------------------------------------------------------------
__global__ __launch_bounds__(512) void gemm_val4(
    const float* __restrict__ A, const u16* __restrict__ Bt2,
    const float* __restrict__ bias2, u16* __restrict__ Vca, u16* __restrict__ Vse)
{
  __shared__ __align__(16) char shraw[33792];   // max(A 32768, stg 33792)
  char* Asw = shraw;
  const int tid  = threadIdx.x;
  const int lane = tid & 63;
  const int w    = tid >> 6;                    // 0..7
  const int bid  = blockIdx.x;
  const int nh   = (bid >> 3) & 1;
  const int m0   = ((bid >> 4) * 8 + (bid & 7)) * 64;
  u16* dst = nh ? Vse : Vca;
  const u16* Bt = Bt2 + nh * 256 * 256;
  const float* bias = bias2 + nh * 256;
  const int b  = m0 / S;
  const int s0 = m0 - b * S;

  // stage A: 64 rows x 256 f32 -> bf16, swizzled (byte ^= (row&7)<<4)
#pragma unroll
  for (int i = 0; i < 4; ++i) {
    const int idx = tid + 512 * i;              // 0..2047
    const int row = idx >> 5, ch = idx & 31;
    const float* ap = A + (size_t)(m0 + row) * 256 + ch * 8;
    const float4 f0 = *(const float4*)(ap);
    const float4 f1 = *(const float4*)(ap + 4);
    uint4 pk;
    pk.x = pk2(f0.x, f0.y); pk.y = pk2(f0.z, f0.w);
    pk.z = pk2(f1.x, f1.y); pk.w = pk2(f1.z, f1.w);
    *(uint4*)(Asw + row * 512 + ((ch * 16) ^ ((row & 7) << 4))) = pk;
  }
  __syncthreads();

  f32x4 acc[4][2] = {};
  const u16* bb = Bt + (size_t)(w * 32 + (lane & 15)) * 256 + (lane >> 4) * 8;
  bf16x8 bcur[2], bnxt[2];
#pragma unroll
  for (int n = 0; n < 2; ++n) bcur[n] = *(const bf16x8*)(bb + n * 4096);

#pragma unroll
  for (int kk = 0; kk < 8; ++kk) {
    bf16x8 af[4];
    const int kb = kk * 64 + (lane >> 4) * 16;
#pragma unroll
    for (int m = 0; m < 4; ++m) {
      const int row = m * 16 + (lane & 15);
      af[m] = *(const bf16x8*)(Asw + row * 512 + (kb ^ ((row & 7) << 4)));
    }
    if (kk < 7) {
#pragma unroll
      for (int n = 0; n < 2; ++n)
        bnxt[n] = *(const bf16x8*)(bb + n * 4096 + (kk + 1) * 32);
    }
#pragma unroll
    for (int m = 0; m < 4; ++m)
#pragma unroll
      for (int n = 0; n < 2; ++n)
        acc[m][n] = __builtin_amdgcn_mfma_f32_16x16x32_bf16(af[m], bcur[n], acc[m][n], 0, 0, 0);
#pragma unroll
    for (int n = 0; n < 2; ++n) bcur[n] = bnxt[n];
  }
  __syncthreads();

  constexpr int STC = 264;
  u16* stg = (u16*)shraw;
  const int cr = (lane >> 4) * 4;
  const int cc = lane & 15;
#pragma unroll
  for (int n = 0; n < 2; ++n) {
    const int col = w * 32 + n * 16 + cc;
    const float bv = bias[col];
#pragma unroll
    for (int m = 0; m < 4; ++m) {
      const int r0 = m * 16 + cr;
#pragma unroll
      for (int r = 0; r < 4; ++r)
        stg[(r0 + r) * STC + col] = f2b(acc[m][n][r] + bv);
    }
  }
  __syncthreads();
  u16* vb = dst + (size_t)b * H * S * DH;
#pragma unroll
  for (int i = 0; i < 4; ++i) {
    const int c = tid + 512 * i;
    const int row = c >> 5, ch = c & 31;
    const int h = ch >> 2, dq = ch & 3;
    *(uint4*)(vb + ((size_t)h * S + (s0 + row)) * DH + dq * 8) =
        *(const uint4*)(&stg[row * STC + ch * 8]);
  }
}

// ---------------------------------------------------------------------------
// Fused GEMM + bias + residual + LN + (y+qpos)->bf16 + off/attn projection.
// (round-15 version; used once, after mha)
// ---------------------------------------------------------------------------
__global__ __launch_bounds__(1024) void gemm_lnoff(
    const u16* __restrict__ A, const u16* __restrict__ Bt,
    const float* __restrict__ bias, const float* __restrict__ res,
    const float* __restrict__ g, const float* __restrict__ be,
    const float* __restrict__ qpos,
    const u16* __restrict__ offw, const float* __restrict__ offb,
    float* __restrict__ fout, float* __restrict__ oaout)
{
  constexpr int K = 256, LDK = 72;
  __shared__ __align__(16) float ftile[64 * 264];
  u16* As = (u16*)ftile;
  u16* Bs = As + 64 * LDK;
  u16* aq = (u16*)ftile;
  const int tid  = threadIdx.x;
  const int lane = tid & 63;
  const int wid  = tid >> 6;
  const int wm = wid >> 2, wn = wid & 3;
  const int m0 = blockIdx.x * 64;

  f32x4 acc[4] = {};
  const bool am = tid < 512;
  const int arow = tid >> 3, ach = (tid & 7) * 8;

  uint4 ra = {};
  uint4 rb[2];
  if (am) ra = *(const uint4*)(A + (size_t)(m0 + arow) * K + ach);
#pragma unroll
  for (int i = 0; i < 2; ++i) {
    const int idx = tid + 1024 * i;
    const int brow = idx >> 3, bch = (idx & 7) * 8;
    rb[i] = *(const uint4*)(Bt + (size_t)brow * K + bch);
  }

  for (int t = 0; t < 4; ++t) {
    if (am) *(uint4*)(&As[arow * LDK + ach]) = ra;
#pragma unroll
    for (int i = 0; i < 2; ++i) {
      const int idx = tid + 1024 * i;
      const int brow = idx >> 3, bch = (idx & 7) * 8;
      *(uint4*)(&Bs[brow * LDK + bch]) = rb[i];
    }
    __syncthreads();
    if (t + 1 < 4) {
      const int k0 = (t + 1) * 64;
      if (am) ra = *(const uint4*)(A + (size_t)(m0 + arow) * K + k0 + ach);
#pragma unroll
      for (int i = 0; i < 2; ++i) {
        const int idx = tid + 1024 * i;
        const int brow = idx >> 3, bch = (idx & 7) * 8;
        rb[i] = *(const uint4*)(Bt + (size_t)brow * K + k0 + bch);
      }
    }
#pragma unroll
    for (int kk = 0; kk < 2; ++kk) {
      const int krd = kk * 32 + (lane >> 4) * 8;
      bf16x8 af, bf[4];
      af = *(const bf16x8*)(&As[(wm * 16 + (lane & 15)) * LDK + krd]);
#pragma unroll
      for (int n = 0; n < 4; ++n)
        bf[n] = *(const bf16x8*)(&Bs[(wn * 64 + n * 16 + (lane & 15)) * LDK + krd]);
#pragma unroll
      for (int n = 0; n < 4; ++n)
        acc[n] = __builtin_amdgcn_mfma_f32_16x16x32_bf16(af, bf[n], acc[n], 0, 0, 0);
    }
    __syncthreads();
  }

  const int cr = (lane >> 4) * 4;
  const int cc = lane & 15;
#pragma unroll
  for (int n = 0; n < 4; ++n) {
    const int col = wn * 64 + n * 16 + cc;
    const float bv = bias[col];
#pragma unroll
    for (int r = 0; r < 4; ++r)
      ftile[(wm * 16 + cr + r) * 264 + col] = acc[n][r] + bv;
  }
  __syncthreads();

  const int row = tid >> 4, s16 = tid & 15;
  const size_t grow = (size_t)(m0 + row) * 256;
  float vv[16];
  float sum = 0.f;
#pragma unroll
  for (int j = 0; j < 4; ++j) {
    const int col = s16 * 4 + j * 64;
    const float4 fv = *(const float4*)(&ftile[row * 264 + col]);
    const float4 rv = *(const float4*)(res + grow + col);
    vv[j * 4 + 0] = fv.x + rv.x; vv[j * 4 + 1] = fv.y + rv.y;
    vv[j * 4 + 2] = fv.z + rv.z; vv[j * 4 + 3] = fv.w + rv.w;
    sum += vv[j * 4 + 0] + vv[j * 4 + 1] + vv[j * 4 + 2] + vv[j * 4 + 3];
  }
  sum += __shfl_xor(sum, 1, 64);
  sum += __shfl_xor(sum, 2, 64);
  sum += __shfl_xor(sum, 4, 64);
  sum += __shfl_xor(sum, 8, 64);
  const float mean = sum * (1.f / 256.f);
  float sq = 0.f;
#pragma unroll
  for (int k = 0; k < 16; ++k) { const float d = vv[k] - mean; sq += d * d; }
  sq += __shfl_xor(sq, 1, 64);
  sq += __shfl_xor(sq, 2, 64);
  sq += __shfl_xor(sq, 4, 64);
  sq += __shfl_xor(sq, 8, 64);
  const float rstd = rsqrtf(sq * (1.f / 256.f) + 1e-5f);

  float yq[16];
#pragma unroll
  for (int j = 0; j < 4; ++j) {
    const int col = s16 * 4 + j * 64;
    const float4 gv = *(const float4*)(g + col);
    const float4 bv = *(const float4*)(be + col);
    const float4 qv = *(const float4*)(qpos + grow + col);
    float4 y;
    y.x = (vv[j * 4 + 0] - mean) * rstd * gv.x + bv.x;
    y.y = (vv[j * 4 + 1] - mean) * rstd * gv.y + bv.y;
    y.z = (vv[j * 4 + 2] - mean) * rstd * gv.z + bv.z;
    y.w = (vv[j * 4 + 3] - mean) * rstd * gv.w + bv.w;
    *(float4*)(fout + grow + col) = y;
    yq[j * 4 + 0] = y.x + qv.x; yq[j * 4 + 1] = y.y + qv.y;
    yq[j * 4 + 2] = y.z + qv.z; yq[j * 4 + 3] = y.w + qv.w;
  }
  __syncthreads();

#pragma unroll
  for (int j = 0; j < 4; ++j) {
    const int col = s16 * 4 + j * 64;
    uint2 pk;
    pk.x = pk2(yq[j * 4 + 0], yq[j * 4 + 1]);
    pk.y = pk2(yq[j * 4 + 2], yq[j * 4 + 3]);
    *(uint2*)(&aq[row * 264 + col]) = pk;
  }
  __syncthreads();

  f32x4 acc2[4] = {};
  const u16* bb = offw + (size_t)(wn * 64 + (lane & 15)) * 256 + (lane >> 4) * 8;
#pragma unroll
  for (int kk = 0; kk < 8; ++kk) {
    const bf16x8 af = *(const bf16x8*)(&aq[(wm * 16 + (lane & 15)) * 264 + kk * 32 + (lane >> 4) * 8]);
#pragma unroll
    for (int n = 0; n < 4; ++n) {
      const bf16x8 bf = *(const bf16x8*)(bb + (size_t)n * 16 * 256 + kk * 32);
      acc2[n] = __builtin_amdgcn_mfma_f32_16x16x32_bf16(af, bf, acc2[n], 0, 0, 0);
    }
  }
  __syncthreads();

#pragma unroll
  for (int n = 0; n < 4; ++n) {
    const int col = wn * 64 + n * 16 + cc;
    const float bv = offb[col];
#pragma unroll
    for (int r = 0; r < 4; ++r)
      ftile[(wm * 16 + cr + r) * 264 + col] = acc2[n][r] + bv;
  }
  __syncthreads();
#pragma unroll
  for (int i = 0; i < 4; ++i) {
    const int c = tid + 1024 * i;
    const int rw = c >> 6, ch = c & 63;
    *(float4*)(oaout + (size_t)(m0 + rw) * 256 + ch * 4) =
        *(const float4*)(&ftile[rw * 264 + ch * 4]);
  }
}

// ---------------------------------------------------------------------------
// Fused ca-deform + out-proj(caout) + LN(ln1) + (y+qpos) + off-proj(seoff).
// 32 rows / 512 thr, grid NQ/32. LDS: Ast @0 (16K), owt @16384 (64K);
// ftile/aq overlay after owt is dead.
// ---------------------------------------------------------------------------
__global__ __launch_bounds__(512) void deform_lnoff(
    const float* __restrict__ oa, const float* __restrict__ ref,
    const u16* __restrict__ value,
    const u16* __restrict__ Wout, const float* __restrict__ bout,
    const float* __restrict__ res, const float* __restrict__ g,
    const float* __restrict__ be, const float* __restrict__ qpos,
    const u16* __restrict__ offw, const float* __restrict__ offb,
    float* __restrict__ fout, float* __restrict__ oaout)
{
  __shared__ __align__(16) char sh[81920];
  char* Ast = sh;                                // [0, 16384)
  uint4* owt = (uint4*)(sh + 16384);             // [16384, 81920)
  float* ftile = (float*)sh;                     // [0, 33792), after owt dead
  u16* aq = (u16*)sh;                            // [0, 16896)
  const int tid  = threadIdx.x;
  const int lane = tid & 63;
  const int w    = tid >> 6;                     // 0..7
  const int m0   = blockIdx.x * 32;
  const int cr = (lane >> 4) * 4;
  const int cc = lane & 15;

  deform_phase<false>(tid, m0, oa, ref, value, owt, Ast);

  // ---- out-proj (caout): wave w -> cols w*32..+31, K=256
  f32x4 accB[2][2] = {};
  {
    const u16* bb = Wout + (size_t)(w * 32 + (lane & 15)) * 256 + (lane >> 4) * 8;
#pragma unroll
    for (int kk = 0; kk < 8; ++kk) {
      bf16x8 af[2];
      const int kb = kk * 64 + (lane >> 4) * 16;
#pragma unroll
      for (int m = 0; m < 2; ++m) {
        const int row = m * 16 + (lane & 15);
        af[m] = *(const bf16x8*)(Ast + row * 512 + (kb ^ ((row & 7) << 4)));
      }
#pragma unroll
      for (int n = 0; n < 2; ++n) {
        const bf16x8 bf = *(const bf16x8*)(bb + (size_t)n * 16 * 256 + kk * 32);
#pragma unroll
        for (int m = 0; m < 2; ++m)
          accB[m][n] = __builtin_amdgcn_mfma_f32_16x16x32_bf16(af[m], bf, accB[m][n], 0, 0, 0);
      }
    }
  }
  __syncthreads();   // Ast + owt consumed

#pragma unroll
  for (int n = 0; n < 2; ++n) {
    const int col = w * 32 + n * 16 + cc;
    const float bv = bout[col];
#pragma unroll
    for (int m = 0; m < 2; ++m)
#pragma unroll
      for (int r = 0; r < 4; ++r)
        ftile[(m * 16 + cr + r) * 264 + col] = accB[m][n][r] + bv;
  }
  __syncthreads();

  // ---- LN (ln1) + qpos
  const int row = tid >> 4, s16 = tid & 15;
  const size_t grow = (size_t)(m0 + row) * 256;
  float yq[16];
  {
    float vv[16];
    float sum = 0.f;
#pragma unroll
    for (int j = 0; j < 4; ++j) {
      const int col = s16 * 4 + j * 64;
      const float4 fv = *(const float4*)(&ftile[row * 264 + col]);
      const float4 rv = *(const float4*)(res + grow + col);
      vv[j * 4 + 0] = fv.x + rv.x; vv[j * 4 + 1] = fv.y + rv.y;
      vv[j * 4 + 2] = fv.z + rv.z; vv[j * 4 + 3] = fv.w + rv.w;
      sum += vv[j * 4 + 0] + vv[j * 4 + 1] + vv[j * 4 + 2] + vv[j * 4 + 3];
    }
    sum += __shfl_xor(sum, 1, 64);
    sum += __shfl_xor(sum, 2, 64);
    sum += __shfl_xor(sum, 4, 64);
    sum += __shfl_xor(sum, 8, 64);
    const float mean = sum * (1.f / 256.f);
    float sq = 0.f;
#pragma unroll
    for (int k = 0; k < 16; ++k) { const float d = vv[k] - mean; sq += d * d; }
    sq += __shfl_xor(sq, 1, 64);
    sq += __shfl_xor(sq, 2, 64);
    sq += __shfl_xor(sq, 4, 64);
    sq += __shfl_xor(sq, 8, 64);
    const float rstd = rsqrtf(sq * (1.f / 256.f) + 1e-5f);
#pragma unroll
    for (int j = 0; j < 4; ++j) {
      const int col = s16 * 4 + j * 64;
      const float4 gv = *(const float4*)(g + col);
      const float4 bv = *(const float4*)(be + col);
      const float4 qv = *(const float4*)(qpos + grow + col);
      float4 y;
      y.x = (vv[j * 4 + 0] - mean) * rstd * gv.x + bv.x;
      y.y = (vv[j * 4 + 1] - mean) * rstd * gv.y + bv.y;
      y.z = (vv[j * 4 + 2] - mean) * rstd * gv.z + bv.z;
      y.w = (vv[j * 4 + 3] - mean) * rstd * gv.w + bv.w;
      *(float4*)(fout + grow + col) = y;
      yq[j * 4 + 0] = y.x + qv.x; yq[j * 4 + 1] = y.y + qv.y;
      yq[j * 4 + 2] = y.z + qv.z; yq[j * 4 + 3] = y.w + qv.w;
    }
  }
  __syncthreads();

#pragma unroll
  for (int j = 0; j < 4; ++j) {
    const int col = s16 * 4 + j * 64;
    uint2 pk;
    pk.x = pk2(yq[j * 4 + 0], yq[j * 4 + 1]);
    pk.y = pk2(yq[j * 4 + 2], yq[j * 4 + 3]);
    *(uint2*)(&aq[row * 264 + col]) = pk;
  }
  __syncthreads();

  // ---- off-proj (seoff|seatt): wave w -> cols w*32..+31, K=256
  f32x4 acc2[2][2] = {};
  {
    const u16* bb = offw + (size_t)(w * 32 + (lane & 15)) * 256 + (lane >> 4) * 8;
#pragma unroll
    for (int kk = 0; kk < 8; ++kk) {
      bf16x8 af[2];
#pragma unroll
      for (int m = 0; m < 2; ++m)
        af[m] = *(const bf16x8*)(&aq[(m * 16 + (lane & 15)) * 264 + kk * 32 + (lane >> 4) * 8]);
#pragma unroll
      for (int n = 0; n < 2; ++n) {
        const bf16x8 bf = *(const bf16x8*)(bb + (size_t)n * 16 * 256 + kk * 32);
#pragma unroll
        for (int m = 0; m < 2; ++m)
          acc2[m][n] = __builtin_amdgcn_mfma_f32_16x16x32_bf16(af[m], bf, acc2[m][n], 0, 0, 0);
      }
    }
  }
  __syncthreads();

#pragma unroll
  for (int n = 0; n < 2; ++n) {
    const int col = w * 32 + n * 16 + cc;
    const float bv = offb[col];
#pragma unroll
    for (int m = 0; m < 2; ++m)
#pragma unroll
      for (int r = 0; r < 4; ++r)
        ftile[(m * 16 + cr + r) * 264 + col] = acc2[m][n][r] + bv;
  }
  __syncthreads();
#pragma unroll
  for (int i = 0; i < 4; ++i) {
    const int c = tid + 512 * i;
    const int rw = c >> 6, ch = c & 63;
    *(float4*)(oaout + (size_t)(m0 + rw) * 256 + ch * 4) =
        *(const float4*)(&ftile[rw * 264 + ch * 4]);
  }
}

// ---------------------------------------------------------------------------
// Fused tail2: se-deform + out-proj(seout) + LN(lnse) + ff1 + relu + ff2 +
// LN(ln3) -> d_out. 32 rows / 512 thr, grid NQ/32.
// LDS: Ast @0 (16K), owt @16384 (64K) during deform; ffh reuses owt region.
// ---------------------------------------------------------------------------
__global__ __launch_bounds__(512) void gemm_tail2(
    const float* __restrict__ oa, const float* __restrict__ ref,
    const u16* __restrict__ value,
    const u16* __restrict__ Wout, const float* __restrict__ bout,
    const float* __restrict__ res,
    const float* __restrict__ g1, const float* __restrict__ be1,
    const u16* __restrict__ B1t, const u16* __restrict__ B2t,
    const float* __restrict__ b1, const float* __restrict__ b2,
    const float* __restrict__ g2, const float* __restrict__ be2,
    float* __restrict__ fout)
{
  __shared__ __align__(16) char sh[81920];
  char* Ast = sh;                               // [0,16K)
  uint4* owt = (uint4*)(sh + 16384);            // [16K,80K) during deform
  char* ffh = sh + 16384;                       // [16K,80K) after deform
  float* ftile = (float*)sh;                    // [0,33792)
  const int tid  = threadIdx.x;
  const int lane = tid & 63;
  const int w    = tid >> 6;
  const int m0   = blockIdx.x * 32;
  const int cr = (lane >> 4) * 4;
  const int cc = lane & 15;

  deform_phase<true>(tid, m0, oa, ref, value, owt, Ast);

  // ---- out-proj (seout): wave w -> cols w*32..+31
  f32x4 accB[2][2] = {};
  {
    const u16* bb = Wout + (size_t)(w * 32 + (lane & 15)) * 256 + (lane >> 4) * 8;
#pragma unroll
    for (int kk = 0; kk < 8; ++kk) {
      bf16x8 af[2];
      const int kb = kk * 64 + (lane >> 4) * 16;
#pragma unroll
      for (int m = 0; m < 2; ++m) {
        const int row = m * 16 + (lane & 15);
        af[m] = *(const bf16x8*)(Ast + row * 512 + (kb ^ ((row & 7) << 4)));
      }
#pragma unroll
      for (int n = 0; n < 2; ++n) {
        const bf16x8 bf = *(const bf16x8*)(bb + (size_t)n * 16 * 256 + kk * 32);
#pragma unroll
        for (int m = 0; m < 2; ++m)
          accB[m][n] = __builtin_amdgcn_mfma_f32_16x16x32_bf16(af[m], bf, accB[m][n], 0, 0, 0);
      }
    }
  }
  __syncthreads();

#pragma unroll
  for (int n = 0; n < 2; ++n) {
    const int col = w * 32 + n * 16 + cc;
    const float bv = bout[col];
#pragma unroll
    for (int m = 0; m < 2; ++m)
#pragma unroll
      for (int r = 0; r < 4; ++r)
        ftile[(m * 16 + cr + r) * 264 + col] = accB[m][n][r] + bv;
  }
  __syncthreads();

  // ---- LN (lnse): y kept in registers
  const int row = tid >> 4, s16 = tid & 15;
  const size_t grow = (size_t)(m0 + row) * 256;
  float yv[16];
  {
    float vv[16];
    float sum = 0.f;
#pragma unroll
    for (int j = 0; j < 4; ++j) {
      const int col = s16 * 4 + j * 64;
      const float4 fv = *(const float4*)(&ftile[row * 264 + col]);
      const float4 rv = *(const float4*)(res + grow + col);
      vv[j * 4 + 0] = fv.x + rv.x; vv[j * 4 + 1] = fv.y + rv.y;
      vv[j * 4 + 2] = fv.z + rv.z; vv[j * 4 + 3] = fv.w + rv.w;
      sum += vv[j * 4 + 0] + vv[j * 4 + 1] + vv[j * 4 + 2] + vv[j * 4 + 3];
    }
    sum += __shfl_xor(sum, 1, 64);
    sum += __shfl_xor(sum, 2, 64);
    sum += __shfl_xor(sum, 4, 64);
    sum += __shfl_xor(sum, 8, 64);
    const float mean = sum * (1.f / 256.f);
    float sq = 0.f;
#pragma unroll
    for (int k = 0; k < 16; ++k) { const float d = vv[k] - mean; sq += d * d; }
    sq += __shfl_xor(sq, 1, 64);
    sq += __shfl_xor(sq, 2, 64);
    sq += __shfl_xor(sq, 4, 64);
    sq += __shfl_xor(sq, 8, 64);
    const float rstd = rsqrtf(sq * (1.f / 256.f) + 1e-5f);
#pragma unroll
    for (int j = 0; j < 4; ++j) {
      const int col = s16 * 4 + j * 64;
      const float4 gv = *(const float4*)(g1 + col);
      const float4 bv = *(const float4*)(be1 + col);
      yv[j * 4 + 0] = (vv[j * 4 + 0] - mean) * rstd * gv.x + bv.x;
      yv[j * 4 + 1] = (vv[j * 4 + 1] - mean) * rstd * gv.y + bv.y;
      yv[j * 4 + 2] = (vv[j * 4 + 2] - mean) * rstd * gv.z + bv.z;
      yv[j * 4 + 3] = (vv[j * 4 + 3] - mean) * rstd * gv.w + bv.w;
    }
  }
  __syncthreads();

  // bf16(y) -> Ast (swizzled)
#pragma unroll
  for (int j = 0; j < 4; ++j) {
    const int col = s16 * 4 + j * 64;
    uint2 pk;
    pk.x = pk2(yv[j * 4 + 0], yv[j * 4 + 1]);
    pk.y = pk2(yv[j * 4 + 2], yv[j * 4 + 3]);
    *(uint2*)(Ast + row * 512 + ((col * 2) ^ ((row & 7) << 4))) = pk;
  }
  __syncthreads();

  // ---- ff1
  {
    f32x4 acc[2][8] = {};
    const u16* bb = B1t + (size_t)(w * 128 + (lane & 15)) * 256 + (lane >> 4) * 8;
#pragma unroll
    for (int kk = 0; kk < 8; ++kk) {
      bf16x8 af[2];
      const int kb = kk * 64 + (lane >> 4) * 16;
#pragma unroll
      for (int m = 0; m < 2; ++m) {
        const int rw = m * 16 + (lane & 15);
        af[m] = *(const bf16x8*)(Ast + rw * 512 + (kb ^ ((rw & 7) << 4)));
      }
#pragma unroll
      for (int n = 0; n < 8; ++n) {
        const bf16x8 bf = *(const bf16x8*)(bb + (size_t)n * 16 * 256 + kk * 32);
#pragma unroll
        for (int m = 0; m < 2; ++m)
          acc[m][n] = __builtin_amdgcn_mfma_f32_16x16x32_bf16(af[m], bf, acc[m][n], 0, 0, 0);
      }
    }
#pragma unroll
    for (int n = 0; n < 8; ++n) {
      const int col = w * 128 + n * 16 + cc;
      const float bv = b1[col];
#pragma unroll
      for (int m = 0; m < 2; ++m) {
#pragma unroll
        for (int r = 0; r < 4; ++r) {
          const int rw = m * 16 + cr + r;
          const float x = fmaxf(acc[m][n][r] + bv, 0.f);
          *(u16*)(ffh + rw * 2048 + ((col * 2) ^ ((rw & 7) << 4))) = f2b(x);
        }
      }
    }
  }
  __syncthreads();

  // ---- ff2
  f32x4 acc2[2][2] = {};
  {
    const u16* bb = B2t + (size_t)(w * 32 + (lane & 15)) * 1024 + (lane >> 4) * 8;
#pragma unroll 4
    for (int kk = 0; kk < 32; ++kk) {
      bf16x8 af[2];
      const int kb = kk * 64 + (lane >> 4) * 16;
#pragma unroll
      for (int m = 0; m < 2; ++m) {
        const int rw = m * 16 + (lane & 15);
        af[m] = *(const bf16x8*)(ffh + rw * 2048 + (kb ^ ((rw & 7) << 4)));
      }
#pragma unroll
      for (int n = 0; n < 2; ++n) {
        const bf16x8 bf = *(const bf16x8*)(bb + (size_t)n * 16 * 1024 + kk * 32);
#pragma unroll
        for (int m = 0; m < 2; ++m)
          acc2[m][n] = __builtin_amdgcn_mfma_f32_16x16x32_bf16(af[m], bf, acc2[m][n], 0, 0, 0);
      }
    }
  }
  __syncthreads();

#pragma unroll
  for (int n = 0; n < 2; ++n) {
    const int col = w * 32 + n * 16 + cc;
    const float bv = b2[col];
#pragma unroll
    for (int m = 0; m < 2; ++m)
#pragma unroll
      for (int r = 0; r < 4; ++r)
        ftile[(m * 16 + cr + r) * 264 + col] = acc2[m][n][r] + bv;
  }
  __syncthreads();

  // ---- final LN (ln3), residual = yv (in registers)
  {
    float vv[16];
    float sum = 0.f;
#pragma unroll
    for (int j = 0; j < 4; ++j) {
      const int col = s16 * 4 + j * 64;
      const float4 fv = *(const float4*)(&ftile[row * 264 + col]);
      vv[j * 4 + 0] = fv.x + yv[j * 4 + 0]; vv[j * 4 + 1] = fv.y + yv[j * 4 + 1];
      vv[j * 4 + 2] = fv.z + yv[j * 4 + 2]; vv[j * 4 + 3] = fv.w + yv[j * 4 + 3];
      sum += vv[j * 4 + 0] + vv[j * 4 + 1] + vv[j * 4 + 2] + vv[j * 4 + 3];
    }
    sum += __shfl_xor(sum, 1, 64);
    sum += __shfl_xor(sum, 2, 64);
    sum += __shfl_xor(sum, 4, 64);
    sum += __shfl_xor(sum, 8, 64);
    const float mean = sum * (1.f / 256.f);
    float sq = 0.f;
#pragma unroll
    for (int k = 0; k < 16; ++k) { const float d = vv[k] - mean; sq += d * d; }
    sq += __shfl_xor(sq, 1, 64);
    sq += __shfl_xor(sq, 2, 64);
    sq += __shfl_xor(sq, 4, 64);
    sq += __shfl_xor(sq, 8, 64);
    const float rstd = rsqrtf(sq * (1.f / 256.f) + 1e-5f);
#pragma unroll
    for (int j = 0; j < 4; ++j) {
      const int col = s16 * 4 + j * 64;
      const float4 gv = *(const float4*)(g2 + col);
      const float4 bv = *(const float4*)(be2 + col);
      float4 y;
      y.x = (vv[j * 4 + 0] - mean) * rstd * gv.x + bv.x;
      y.y = (vv[j * 4 + 1] - mean) * rstd * gv.y + bv.y;
      y.z = (vv[j * 4 + 2] - mean) * rstd * gv.z + bv.z;
      y.w = (vv[j * 4 + 3] - mean) * rstd * gv.w + bv.w;
      *(float4*)(fout + grow + col) = y;
    }
  }
}

// ---------------------------------------------------------------------------
// prep_all (round-8 version).
// ---------------------------------------------------------------------------
struct WSpec { const float* w; u16* wt; int K, N, blk0; };
struct WPack { WSpec s[14]; };

struct PrepArgs {
  const float *ca_off_b, *ca_attn_b, *se_off_b, *se_attn_b;
  const float *sa_qb, *sa_kb, *ca_val_b, *se_val_b;
  float *bias4, *qkb, *valb;
  const float *tgt, *qpos;
  u16 *tgtb, *qbuf;
  int n4, nwt;
};

__global__ __launch_bounds__(256) void prep_all(WPack p, PrepArgs a) {
  __shared__ float tile[32][33];
  const int b = blockIdx.x;
  if (b < a.nwt) {
    int i = 0;
#pragma unroll
    for (int j = 1; j < 14; ++j) if (b >= p.s[j].blk0) i = j;
    const float* w = p.s[i].w;
    u16* wt = p.s[i].wt;
    const int K = p.s[i].K, N = p.s[i].N;
    const int lb = b - p.s[i].blk0;
    const int ntN = N >> 5;
    const int tk = lb / ntN, tn = lb - tk * ntN;
    const int r = threadIdx.x >> 5, c = threadIdx.x & 31;
#pragma unroll
    for (int j = 0; j < 4; ++j)
      tile[r + j * 8][c] = w[(size_t)(tk * 32 + r + j * 8) * N + tn * 32 + c];
    __syncthreads();
#pragma unroll
    for (int j = 0; j < 4; ++j)
      wt[(size_t)(tn * 32 + r + j * 8) * K + tk * 32 + c] = f2b(tile[c][r + j * 8]);
  } else if (b == a.nwt) {
#pragma unroll
    for (int u = 0; u < 2; ++u) {
      const int t = threadIdx.x + 256 * u;
      a.bias4[t] = t < 128 ? a.ca_off_b[t] : t < 256 ? a.ca_attn_b[t - 128]
                 : t < 384 ? a.se_off_b[t - 256] : a.se_attn_b[t - 384];
      a.qkb[t]  = t < 256 ? a.sa_qb[t] : a.sa_kb[t - 256];
      a.valb[t] = t < 256 ? a.ca_val_b[t] : a.se_val_b[t - 256];
    }
  } else {
    const int i = (b - a.nwt - 1) * 256 + threadIdx.x;
    if (i < a.n4) {
      const float4 t = ((const float4*)a.tgt)[i];
      const float4 q = ((const float4*)a.qpos)[i];
      uint2 x, y;
      x.x = pk2(t.x, t.y); x.y = pk2(t.z, t.w);
      y.x = pk2(t.x + q.x, t.y + q.y); y.y = pk2(t.z + q.z, t.w + q.w);
      ((uint2*)a.tgtb)[i] = x;
      ((uint2*)a.qbuf)[i] = y;
    }
  }
}

// ---------------------------------------------------------------------------
// Self-attention: split-K softmax. (round-6 version)
// ---------------------------------------------------------------------------
__global__ __launch_bounds__(512) void mha_v2(
    const u16* __restrict__ qk, const u16* __restrict__ vh,
    u16* __restrict__ out)
{
  __shared__ __align__(16) float Ks[8 * 300 * 4];
  __shared__ __align__(16) float Vs[8 * 300 * 4];
  const int bh  = blockIdx.x & 255;
  const int seg = blockIdx.x >> 8;
  const int b = bh >> 3, h = bh & 7;
  const u16* kbase = qk + (size_t)b * LQ * 512 + 256 + h * DH;
  const u16* vbase = vh + (size_t)b * LQ * D + h * DH;
  for (int e = threadIdx.x; e < 300 * 8; e += 512) {
    const int r = e >> 3, j = e & 7;
    float4 f;
    const uint2 kv = *(const uint2*)(kbase + (size_t)r * 512 + j * 4);
    unpack2(kv.x, f.x, f.y);
    unpack2(kv.y, f.z, f.w);
    *(float4*)(&Ks[(j * 300 + r) * 4]) = f;
    const uint2 vv = *(const uint2*)(vbase + (size_t)r * D + j * 4);
    unpack2(vv.x, f.x, f.y);
    unpack2(vv.y, f.z, f.w);
    *(float4*)(&Vs[(j * 300 + r) * 4]) = f;
  }
  __syncthreads();

  const int lane = threadIdx.x & 63;
  const int lq = (threadIdx.x >> 6) * 16 + (lane >> 2);
  const int kc = lane & 3;
  const int q = seg * 128 + lq;
  if (q >= LQ) return;

  const u16* qrow = qk + (size_t)(b * LQ + q) * 512 + h * DH;
  float qv[DH];
#pragma unroll
  for (int c4 = 0; c4 < 4; ++c4) {
    const uint4 u = *(const uint4*)(qrow + c4 * 8);
    unpack2(u.x, qv[c4 * 8 + 0], qv[c4 * 8 + 1]);
    unpack2(u.y, qv[c4 * 8 + 2], qv[c4 * 8 + 3]);
    unpack2(u.z, qv[c4 * 8 + 4], qv[c4 * 8 + 5]);
    unpack2(u.w, qv[c4 * 8 + 6], qv[c4 * 8 + 7]);
  }
#pragma unroll
  for (int d = 0; d < DH; ++d) qv[d] *= 0.17677669529663689f;

  float o[DH] = {};
  float ssum = 0.f;
  const float* kp = &Ks[kc * 75 * 4];
  const float* vp = &Vs[kc * 75 * 4];
  for (int i = 0; i < 75; ++i) {
    float s = 0.f;
#pragma unroll
    for (int j = 0; j < 8; ++j) {
      const float4 kf = *(const float4*)(kp + i * 4 + j * 1200);
      s += qv[j * 4 + 0] * kf.x + qv[j * 4 + 1] * kf.y
         + qv[j * 4 + 2] * kf.z + qv[j * 4 + 3] * kf.w;
    }
    const float p = __expf(s);
    ssum += p;
#pragma unroll
    for (int j = 0; j < 8; ++j) {
      const float4 vf = *(const float4*)(vp + i * 4 + j * 1200);
      o[j * 4 + 0] += p * vf.x; o[j * 4 + 1] += p * vf.y;
      o[j * 4 + 2] += p * vf.z; o[j * 4 + 3] += p * vf.w;
    }
  }

  ssum += __shfl_xor(ssum, 1, 64);
  ssum += __shfl_xor(ssum, 2, 64);
#pragma unroll
  for (int d = 0; d < DH; ++d) {
    o[d] += __shfl_xor(o[d], 1, 64);
    o[d] += __shfl_xor(o[d], 2, 64);
  }
  const float inv = 1.f / ssum;

  u16* orow = out + (size_t)(b * LQ + q) * D + h * DH;
#pragma unroll
  for (int c = 0; c < 4; ++c) {
    if (kc == c) {
      uint4 w;
      w.x = pk2(o[c * 8 + 0] * inv, o[c * 8 + 1] * inv);
      w.y = pk2(o[c * 8 + 2] * inv, o[c * 8 + 3] * inv);
      w.z = pk2(o[c * 8 + 4] * inv, o[c * 8 + 5] * inv);
      w.w = pk2(o[c * 8 + 6] * inv, o[c * 8 + 7] * inv);
      *(uint4*)(orow + c * 8) = w;
    }
  }
}

}  // namespace

extern "C" void kernel_launch(void* const* d_in, const int* in_sizes, int n_in,
                              void* d_out, int out_size, void* d_ws, size_t ws_size,
                              hipStream_t stream)
{
  const float* tgt   = (const float*)d_in[0];
  const float* qpos  = (const float*)d_in[1];
  const float* ref   = (const float*)d_in[2];
  const float* src   = (const float*)d_in[3];
  const float* sa_qw = (const float*)d_in[6];
  const float* sa_kw = (const float*)d_in[7];
  const float* sa_vw = (const float*)d_in[8];
  const float* sa_ow = (const float*)d_in[9];
  const float* ff1_w = (const float*)d_in[10];
  const float* ff2_w = (const float*)d_in[11];
  const float* sa_qb = (const float*)d_in[12];
  const float* sa_kb = (const float*)d_in[13];
  const float* sa_vb = (const float*)d_in[14];
  const float* sa_ob = (const float*)d_in[15];
  const float* ff1_b = (const float*)d_in[16];
  const float* ff2_b = (const float*)d_in[17];
  const float* ca_off_w  = (const float*)d_in[18];
  const float* ca_off_b  = (const float*)d_in[19];
  const float* ca_attn_w = (const float*)d_in[20];
  const float* ca_attn_b = (const float*)d_in[21];
  const float* ca_val_w  = (const float*)d_in[22];
  const float* ca_val_b  = (const float*)d_in[23];
  const float* ca_out_w  = (const float*)d_in[24];
  const float* ca_out_b  = (const float*)d_in[25];
  const float* se_off_w  = (const float*)d_in[26];
  const float* se_off_b  = (const float*)d_in[27];
  const float* se_attn_w = (const float*)d_in[28];
  const float* se_attn_b = (const float*)d_in[29];
  const float* se_val_w  = (const float*)d_in[30];
  const float* se_val_b  = (const float*)d_in[31];
  const float* se_out_w  = (const float*)d_in[32];
  const float* se_out_b  = (const float*)d_in[33];
  const float* ln1_g  = (const float*)d_in[34];
  const float* ln1_b  = (const float*)d_in[35];
  const float* lnse_g = (const float*)d_in[36];
  const float* lnse_b = (const float*)d_in[37];
  const float* ln2_g  = (const float*)d_in[38];
  const float* ln2_b  = (const float*)d_in[39];
  const float* ln3_g  = (const float*)d_in[40];
  const float* ln3_b  = (const float*)d_in[41];

  const size_t ND = (size_t)NQ * D;       // 2,457,600
  const size_t MD = (size_t)MS * D;       // 31,457,280

  char* base = (char*)d_ws;
  size_t off = 0;
  auto alloc = [&](size_t bytes) -> void* {
    void* p = base + off;
    off += (bytes + 255) & ~(size_t)255;
    return p;
  };
  u16*  Vca  = (u16*)alloc(MD * 2);
  u16*  Vse  = (u16*)alloc(MD * 2);
  u16*  qkbuf = (u16*)alloc((size_t)NQ * 512 * 2);
  u16*  vh   = (u16*)alloc(ND * 2);
  u16*  qbuf = (u16*)alloc(ND * 2);
  u16*  smpb = (u16*)alloc(ND * 2);
  u16*  tgtb = (u16*)alloc(ND * 2);
  float* cur = (float*)alloc(ND * 4);
  float* oabuf = (float*)alloc((size_t)NQ * 256 * 4);
  float* bias4 = (float*)alloc(512 * 4);
  float* qkb   = (float*)alloc(512 * 4);
  float* valb  = (float*)alloc(512 * 4);

  WPack pk;
  int wi = 0, blk = 0;
  auto addw = [&](const float* w, int K, int N) -> u16* {
    u16* wt = (u16*)alloc((size_t)K * N * 2);
    pk.s[wi].w = w; pk.s[wi].wt = wt; pk.s[wi].K = K; pk.s[wi].N = N; pk.s[wi].blk0 = blk;
    blk += (K / 32) * (N / 32);
    ++wi;
    return wt;
  };
  u16* saq_t = addw(sa_qw, D, D);
  u16* sak_t = addw(sa_kw, D, D);        (void)sak_t;
  u16* sav_t = addw(sa_vw, D, D);
  u16* sao_t = addw(sa_ow, D, D);
  u16* ff1_t = addw(ff1_w, D, DFFN);
  u16* ff2_t = addw(ff2_w, DFFN, D);
  u16* caoff_t = addw(ca_off_w, D, 128);
  u16* caatt_t = addw(ca_attn_w, D, 128);  (void)caatt_t;
  u16* seoff_t = addw(se_off_w, D, 128);
  u16* seatt_t = addw(se_attn_w, D, 128);  (void)seatt_t;
  u16* caval_t = addw(ca_val_w, D, D);
  u16* seval_t = addw(se_val_w, D, D);     (void)seval_t;
  u16* caout_t = addw(ca_out_w, D, D);
  u16* seout_t = addw(se_out_w, D, D);

  const int n4 = (int)(ND / 4);            // 614400

  // ---- prep (weights + biases + tgt/qpos) in ONE dispatch ----
  PrepArgs pa;
  pa.ca_off_b = ca_off_b; pa.ca_attn_b = ca_attn_b;
  pa.se_off_b = se_off_b; pa.se_attn_b = se_attn_b;
  pa.sa_qb = sa_qb; pa.sa_kb = sa_kb; pa.ca_val_b = ca_val_b; pa.se_val_b = se_val_b;
  pa.bias4 = bias4; pa.qkb = qkb; pa.valb = valb;
  pa.tgt = tgt; pa.qpos = qpos; pa.tgtb = tgtb; pa.qbuf = qbuf;
  pa.n4 = n4; pa.nwt = blk;
  prep_all<<<blk + 1 + 2400, 256, 0, stream>>>(pk, pa);

  gemm_val4<<<(MS / 64) * 2, 512, 0, stream>>>(src, caval_t, valb, Vca, Vse);

  // ---- self-attention ----
  gemm_qkv<<<dim3(12, 150), 256, 0, stream>>>(qbuf, tgtb, saq_t, sav_t, qkb, sa_vb, qkbuf, vh);
  mha_v2<<<B * H * 3, 512, 0, stream>>>(qkbuf, vh, smpb);
  gemm_lnoff<<<NQ / 64, 1024, 0, stream>>>(smpb, sao_t, sa_ob, tgt, ln2_g, ln2_b,
                                           qpos, caoff_t, bias4, cur, oabuf);

  // ---- ca deform + out-proj + LN(ln1) + seoff projection (fused) ----
  deform_lnoff<<<NQ / 32, 512, 0, stream>>>(oabuf, ref, Vca,
                                            caout_t, ca_out_b, cur, ln1_g, ln1_b,
                                            qpos, seoff_t, bias4 + 256, cur, oabuf);

  // ---- se deform + out-proj + LN(lnse) + FFN + LN(ln3) -> d_out (fused) ----
  gemm_tail2<<<NQ / 32, 512, 0, stream>>>(oabuf, ref, Vse,
                                          seout_t, se_out_b, cur,
                                          lnse_g, lnse_b, ff1_t, ff2_t,
                                          ff1_b, ff2_b, ln3_g, ln3_b,
                                          (float*)d_out);
}